// Round 2
// baseline (358.326 us; speedup 1.0000x reference)
//
#include <hip/hip_runtime.h>
#include <math.h>

#define B_    32
#define C_    128
#define N_    64
#define HID_  256
#define PIX_  4096
#define STEEP 50.0f
#define INV_PI 0.318309886183790671f
#define LDH   272  // LDS row pitch (u16): 32 h1 chunks (256) + 16 pad; x tile time-shares cols 128..255
#define LDX   72   // k5 pitch

typedef unsigned short u16;
typedef __attribute__((ext_vector_type(8))) short bf16x8;
typedef __attribute__((ext_vector_type(4))) float f32x4;

__device__ __forceinline__ u16 f2bf(float f) {
    unsigned int u = __builtin_bit_cast(unsigned int, f);
    unsigned int r = (u + 0x7FFFu + ((u >> 16) & 1u)) >> 16;
    return (u16)r;
}
__device__ __forceinline__ float bf2f(u16 h) {
    unsigned int u = ((unsigned int)h) << 16;
    return __builtin_bit_cast(float, u);
}
// swizzled LDS indices (chunk = 8 u16 = 16 B, rotated by row for bank spread)
__device__ __forceinline__ int h1_idx(int p, int k) {
    return p * LDH + (((k >> 3) + (p & 7)) & 31) * 8 + (k & 7);
}
__device__ __forceinline__ int x_idx(int p, int k) {
    return p * LDH + 128 + (((k >> 3) + (p & 7)) & 15) * 8 + (k & 7);
}

// ---------------- K0: init score buffers with biases ----------------
__global__ void k0_init(float* __restrict__ row_s, float* __restrict__ col_s,
                        const float* __restrict__ b_row, const float* __restrict__ b_col) {
    int i = blockIdx.x * 256 + threadIdx.x;
    if (i < B_ * N_) {
        row_s[i] = b_row[0];
        col_s[i] = b_col[0];
    }
}

// ---------------- Kprep: decompose weights into bf16 hi/lo ----------------
__global__ void k_prep(const float* __restrict__ w1, const float* __restrict__ w2,
                       u16* __restrict__ w1h, u16* __restrict__ w1l,
                       u16* __restrict__ w2h, u16* __restrict__ w2l) {
    int i = blockIdx.x * 256 + threadIdx.x;
    if (i < HID_ * C_) {
        float v = w1[i];
        u16 h = f2bf(v);
        w1h[i] = h;
        w1l[i] = f2bf(v - bf2f(h));
    } else {
        int j = i - HID_ * C_;
        if (j < HID_ * HID_) {
            float v = w2[j];
            u16 h = f2bf(v);
            w2h[j] = h;
            w2l[j] = f2bf(v - bf2f(h));
        }
    }
}

// ---------------- K12: fused conv1+conv2+scores, 32-pixel tiles ----------------
// NOTE: plain __launch_bounds__(256): the (256,4) variant made the allocator
// chase the 64-VGPR tier and spill the conv2 pipeline to scratch (R1: 210us).
// LDS (35328B -> 4 blocks/CU) is the occupancy cap; ~112 VGPR fits 4 waves/SIMD.
__global__ __launch_bounds__(256) void k12_fused(
    const float* __restrict__ x,
    const u16* __restrict__ w1h, const u16* __restrict__ w1l,
    const float* __restrict__ b1,
    const u16* __restrict__ w2h, const u16* __restrict__ w2l,
    const float* __restrict__ b2, const float* __restrict__ w_row,
    const float* __restrict__ w_col,
    float* __restrict__ row_s, float* __restrict__ col_s) {
    __shared__ __align__(16) u16 Lh[32 * LDH];   // 17408 B (h1 hi / x hi staging)
    __shared__ __align__(16) u16 Ll[32 * LDH];   // 17408 B (h1 lo / x lo staging)
    __shared__ float col_red[32];
    __shared__ float row_red;

    const int t = threadIdx.x;
    const int l = t & 63, w = t >> 6;
    const int col = l & 15, q = l >> 4;
    const int hrow = blockIdx.x >> 1;
    const int half = blockIdx.x & 1;
    const int b = blockIdx.y;
    const float* xb = x + (size_t)b * C_ * PIX_ + hrow * 64 + half * 32;

    if (t < 32) col_red[t] = 0.f;
    if (t == 0) row_red = 0.f;

    // ---- stage x tile [32 p][128 c] -> swizzled cols 128..255 (one barrier) ----
    {
        const int pt = t & 7, ct = t >> 3;       // pt 0..7 (4 pixels each), ct 0..31
#pragma unroll
        for (int cc = 0; cc < 2; cc++) {
            const int c = cc * 64 + 2 * ct;
            float4 v0 = *(const float4*)&xb[(size_t)c * PIX_ + pt * 4];
            float4 v1 = *(const float4*)&xb[(size_t)(c + 1) * PIX_ + pt * 4];
            float a0[4] = {v0.x, v0.y, v0.z, v0.w};
            float a1[4] = {v1.x, v1.y, v1.z, v1.w};
#pragma unroll
            for (int j = 0; j < 4; j++) {
                int p = pt * 4 + j;
                u16 h0 = f2bf(a0[j]), h1v = f2bf(a1[j]);
                u16 l0 = f2bf(a0[j] - bf2f(h0)), l1 = f2bf(a1[j] - bf2f(h1v));
                int idx = x_idx(p, c);
                *(unsigned int*)&Lh[idx] = (unsigned int)h0 | ((unsigned int)h1v << 16);
                *(unsigned int*)&Ll[idx] = (unsigned int)l0 | ((unsigned int)l1 << 16);
            }
        }
    }
    __syncthreads();

    // ---- conv1: pipelined A (global) + B (LDS) ----
    f32x4 acc[4][2];
#pragma unroll
    for (int i = 0; i < 4; i++)
#pragma unroll
        for (int j = 0; j < 2; j++) acc[i][j] = (f32x4){0.f, 0.f, 0.f, 0.f};

    bf16x8 ah[4], al_[4];
#pragma unroll
    for (int mf = 0; mf < 4; mf++) {
        size_t ro = (size_t)(64 * w + 16 * mf + col) * C_ + q * 8;
        ah[mf] = *(const bf16x8*)&w1h[ro];
        al_[mf] = *(const bf16x8*)&w1l[ro];
    }
#pragma unroll
    for (int kc = 0; kc < 4; kc++) {
        bf16x8 bh[2], bl[2];
#pragma unroll
        for (int nt = 0; nt < 2; nt++) {
            int idx = x_idx(nt * 16 + col, kc * 32 + q * 8);
            bh[nt] = *(const bf16x8*)&Lh[idx];
            bl[nt] = *(const bf16x8*)&Ll[idx];
        }
        bf16x8 ahn[4], aln[4];
        const int kn = (kc + 1) & 3;
#pragma unroll
        for (int mf = 0; mf < 4; mf++) {
            size_t ro = (size_t)(64 * w + 16 * mf + col) * C_ + kn * 32 + q * 8;
            ahn[mf] = *(const bf16x8*)&w1h[ro];
            aln[mf] = *(const bf16x8*)&w1l[ro];
        }
#pragma unroll
        for (int mf = 0; mf < 4; mf++)
#pragma unroll
            for (int nt = 0; nt < 2; nt++) {
                acc[mf][nt] = __builtin_amdgcn_mfma_f32_16x16x32_bf16(ah[mf], bh[nt], acc[mf][nt], 0, 0, 0);
                acc[mf][nt] = __builtin_amdgcn_mfma_f32_16x16x32_bf16(ah[mf], bl[nt], acc[mf][nt], 0, 0, 0);
                acc[mf][nt] = __builtin_amdgcn_mfma_f32_16x16x32_bf16(al_[mf], bh[nt], acc[mf][nt], 0, 0, 0);
            }
#pragma unroll
        for (int mf = 0; mf < 4; mf++) { ah[mf] = ahn[mf]; al_[mf] = aln[mf]; }
    }

    // prefetch conv2's first A-frags before the barrier
    bf16x8 ah2[4], al2[4];
#pragma unroll
    for (int mf = 0; mf < 4; mf++) {
        size_t ro = (size_t)(64 * w + 16 * mf + col) * HID_ + q * 8;
        ah2[mf] = *(const bf16x8*)&w2h[ro];
        al2[mf] = *(const bf16x8*)&w2l[ro];
    }
    __syncthreads();   // all x-frag reads done; rows can be overwritten with h1

    // ---- conv1 epilogue: relu(acc+b1) -> swizzled h1 hi/lo ----
#pragma unroll
    for (int mf = 0; mf < 4; mf++) {
        int o = 64 * w + 16 * mf + q * 4;
        float bias[4];
#pragma unroll
        for (int r = 0; r < 4; r++) bias[r] = b1[o + r];
#pragma unroll
        for (int nt = 0; nt < 2; nt++) {
            int p = nt * 16 + col;
            u16 hh[4], ll[4];
#pragma unroll
            for (int r = 0; r < 4; r++) {
                float v = fmaxf(acc[mf][nt][r] + bias[r], 0.f);
                u16 h = f2bf(v);
                hh[r] = h;
                ll[r] = f2bf(v - bf2f(h));
            }
            int idx = h1_idx(p, o);
            *(unsigned long long*)&Lh[idx] =
                (unsigned long long)hh[0] | ((unsigned long long)hh[1] << 16) |
                ((unsigned long long)hh[2] << 32) | ((unsigned long long)hh[3] << 48);
            *(unsigned long long*)&Ll[idx] =
                (unsigned long long)ll[0] | ((unsigned long long)ll[1] << 16) |
                ((unsigned long long)ll[2] << 32) | ((unsigned long long)ll[3] << 48);
        }
    }
    __syncthreads();

    // ---- conv2: pipelined ----
    f32x4 acc2[4][2];
#pragma unroll
    for (int i = 0; i < 4; i++)
#pragma unroll
        for (int j = 0; j < 2; j++) acc2[i][j] = (f32x4){0.f, 0.f, 0.f, 0.f};

#pragma unroll
    for (int kc = 0; kc < 8; kc++) {
        bf16x8 bh[2], bl[2];
#pragma unroll
        for (int nt = 0; nt < 2; nt++) {
            int idx = h1_idx(nt * 16 + col, kc * 32 + q * 8);
            bh[nt] = *(const bf16x8*)&Lh[idx];
            bl[nt] = *(const bf16x8*)&Ll[idx];
        }
        bf16x8 ahn[4], aln[4];
        const int kn = (kc + 1) & 7;
#pragma unroll
        for (int mf = 0; mf < 4; mf++) {
            size_t ro = (size_t)(64 * w + 16 * mf + col) * HID_ + kn * 32 + q * 8;
            ahn[mf] = *(const bf16x8*)&w2h[ro];
            aln[mf] = *(const bf16x8*)&w2l[ro];
        }
#pragma unroll
        for (int mf = 0; mf < 4; mf++)
#pragma unroll
            for (int nt = 0; nt < 2; nt++) {
                acc2[mf][nt] = __builtin_amdgcn_mfma_f32_16x16x32_bf16(ah2[mf], bh[nt], acc2[mf][nt], 0, 0, 0);
                acc2[mf][nt] = __builtin_amdgcn_mfma_f32_16x16x32_bf16(ah2[mf], bl[nt], acc2[mf][nt], 0, 0, 0);
                acc2[mf][nt] = __builtin_amdgcn_mfma_f32_16x16x32_bf16(al2[mf], bh[nt], acc2[mf][nt], 0, 0, 0);
            }
#pragma unroll
        for (int mf = 0; mf < 4; mf++) { ah2[mf] = ahn[mf]; al2[mf] = aln[mf]; }
    }

    // ---- score epilogue ----
    float rpart = 0.f;
    float cpart[2] = {0.f, 0.f};
#pragma unroll
    for (int mf = 0; mf < 4; mf++) {
        int o = 64 * w + 16 * mf + q * 4;
#pragma unroll
        for (int r = 0; r < 4; r++) {
            float bias = b2[o + r];
            float wcv = w_col[(o + r) * N_ + hrow];
#pragma unroll
            for (int nt = 0; nt < 2; nt++) {
                int wc = nt * 16 + col;
                float v = fmaxf(acc2[mf][nt][r] + bias, 0.f);
                rpart += v * w_row[(o + r) * N_ + half * 32 + wc];
                cpart[nt] += v * wcv;
            }
        }
    }
#pragma unroll
    for (int off = 32; off; off >>= 1) rpart += __shfl_xor(rpart, off, 64);
    if (l == 0) atomicAdd(&row_red, rpart);
#pragma unroll
    for (int nt = 0; nt < 2; nt++) {
        float cp = cpart[nt];
        cp += __shfl_xor(cp, 16, 64);
        cp += __shfl_xor(cp, 32, 64);
        if (l < 16) atomicAdd(&col_red[nt * 16 + l], cp);
    }
    __syncthreads();
    if (t < 32) atomicAdd(&col_s[b * N_ + half * 32 + t], col_red[t]);
    if (t == 0) atomicAdd(&row_s[b * N_ + hrow], row_red);
}

// ---------------- K4: diff bitonic sort, register-resident P, shuffle-only ----------------
__global__ __launch_bounds__(256) void k4_diffsort(const float* __restrict__ row_s,
                                                   const float* __restrict__ col_s,
                                                   u16* __restrict__ prow_h, u16* __restrict__ prow_l,
                                                   u16* __restrict__ pcol_h, u16* __restrict__ pcol_l) {
    const int t = threadIdx.x;
    const int lane = t & 63, w = t >> 6;
    const int which = blockIdx.x & 1;
    const int b = blockIdx.x >> 1;
    const float* sc = which ? col_s : row_s;
    u16* Ph = which ? pcol_h : prow_h;
    u16* Pl = which ? pcol_l : prow_l;

    float xv = sc[b * 64 + lane];
    float P[16];
#pragma unroll
    for (int r = 0; r < 16; r++) P[r] = ((w * 16 + r) == lane) ? 1.f : 0.f;

#pragma unroll
    for (int bl = 0; bl < 6; bl++) {
#pragma unroll
        for (int ly = 0; ly <= bl; ly++) {
            const int sh = bl - ly;
            const int m = 1 << sh;
            float xp = __shfl_xor(xv, m, 64);
            int lower = ((lane >> sh) & 1) ^ 1;            // lane is the low member of its pair
            int swp = (lane >> (bl + 1)) & 1;              // direction flip for this pair
            float diff = (lower ^ swp) ? (xp - xv) : (xv - xp);   // xb - xa (same value both lanes)
            float al = atanf(diff * STEEP) * INV_PI + 0.5f;
            xv = al * xv + (1.f - al) * xp;
#pragma unroll
            for (int r = 0; r < 16; r++) {
                float Pp = __shfl_xor(P[r], m, 64);
                P[r] = al * P[r] + (1.f - al) * Pp;
            }
        }
    }
#pragma unroll
    for (int r = 0; r < 16; r++) {
        float v = P[r];
        u16 h = f2bf(v);
        int row = w * 16 + r;
        Ph[(size_t)b * 4096 + row * 64 + lane] = h;
        Pl[(size_t)b * 4096 + row * 64 + lane] = f2bf(v - bf2f(h));
    }
}

// ---------------- K5: fused double permutation via MFMA, one channel/block ----------------
// R2: was 1024 blocks x 4 serial channels (8 barriers in a chain); now 4096
// blocks x 1 channel, 1 barrier. Inter-block TLP hides stage->compute latency.
__global__ __launch_bounds__(256) void k5_permute(const float* __restrict__ x,
                                                  const u16* __restrict__ pcol_h,
                                                  const u16* __restrict__ pcol_l,
                                                  const u16* __restrict__ prow_h,
                                                  const u16* __restrict__ prow_l,
                                                  float* __restrict__ out) {
    __shared__ __align__(16) u16 Xh[64 * LDX];
    __shared__ __align__(16) u16 Xl[64 * LDX];
    __shared__ __align__(16) u16 Zh[64 * LDX];
    __shared__ __align__(16) u16 Zl[64 * LDX];
    const int t = threadIdx.x;
    const int l = t & 63, w = t >> 6;
    const int col = l & 15, q = l >> 4;
    const int b = blockIdx.y;
    const int c = blockIdx.x;
    const int i0 = w * 16;

    const u16* pch = pcol_h + (size_t)b * 4096;
    const u16* pcl = pcol_l + (size_t)b * 4096;
    const u16* prh = prow_h + (size_t)b * 4096;
    const u16* prl = prow_l + (size_t)b * 4096;

    // P_col A-frags: issue before staging so global latency overlaps conversion
    bf16x8 pcA_h[2], pcA_l[2];
#pragma unroll
    for (int ks = 0; ks < 2; ks++) {
        pcA_h[ks] = *(const bf16x8*)&pch[(i0 + col) * 64 + q * 8 + ks * 32];
        pcA_l[ks] = *(const bf16x8*)&pcl[(i0 + col) * 64 + q * 8 + ks * 32];
    }

    const float* xc = x + ((size_t)b * C_ + c) * PIX_;
#pragma unroll
    for (int k = 0; k < 4; k++) {
        int f = t + k * 256;
        int rw = f >> 4, c4 = f & 15;
        float4 v = *(const float4*)&xc[f * 4];
        u16 h0 = f2bf(v.x), h1 = f2bf(v.y), h2 = f2bf(v.z), h3 = f2bf(v.w);
        ushort4 hv = {h0, h1, h2, h3};
        ushort4 lv = {f2bf(v.x - bf2f(h0)), f2bf(v.y - bf2f(h1)),
                      f2bf(v.z - bf2f(h2)), f2bf(v.w - bf2f(h3))};
        *(ushort4*)&Xh[rw * LDX + c4 * 4] = hv;
        *(ushort4*)&Xl[rw * LDX + c4 * 4] = lv;
    }
    __syncthreads();

    f32x4 acc[4];
#pragma unroll
    for (int nt = 0; nt < 4; nt++) acc[nt] = (f32x4){0.f, 0.f, 0.f, 0.f};
#pragma unroll
    for (int ks = 0; ks < 2; ks++) {
        bf16x8 ah = pcA_h[ks], al_ = pcA_l[ks];
#pragma unroll
        for (int nt = 0; nt < 4; nt++) {
            bf16x8 bh = *(const bf16x8*)&Xh[(nt * 16 + col) * LDX + q * 8 + ks * 32];
            bf16x8 bl = *(const bf16x8*)&Xl[(nt * 16 + col) * LDX + q * 8 + ks * 32];
            acc[nt] = __builtin_amdgcn_mfma_f32_16x16x32_bf16(ah, bh, acc[nt], 0, 0, 0);
            acc[nt] = __builtin_amdgcn_mfma_f32_16x16x32_bf16(ah, bl, acc[nt], 0, 0, 0);
            acc[nt] = __builtin_amdgcn_mfma_f32_16x16x32_bf16(al_, bh, acc[nt], 0, 0, 0);
        }
    }
    // Z tiles are wave-private (wave w writes rows i0..i0+15, reads the same):
    // compiler's shared-array aliasing inserts the lgkm wait; no barrier needed.
#pragma unroll
    for (int nt = 0; nt < 4; nt++)
#pragma unroll
        for (int r = 0; r < 4; r++) {
            float v = acc[nt][r];
            u16 h = f2bf(v);
            int rw = i0 + q * 4 + r;
            Zh[rw * LDX + nt * 16 + col] = h;
            Zl[rw * LDX + nt * 16 + col] = f2bf(v - bf2f(h));
        }

    f32x4 acc2[4];
#pragma unroll
    for (int nt = 0; nt < 4; nt++) acc2[nt] = (f32x4){0.f, 0.f, 0.f, 0.f};
#pragma unroll
    for (int ks = 0; ks < 2; ks++) {
        bf16x8 ah = *(const bf16x8*)&Zh[(i0 + col) * LDX + q * 8 + ks * 32];
        bf16x8 al_ = *(const bf16x8*)&Zl[(i0 + col) * LDX + q * 8 + ks * 32];
#pragma unroll
        for (int nt = 0; nt < 4; nt++) {
            bf16x8 bh = *(const bf16x8*)&prh[(nt * 16 + col) * 64 + q * 8 + ks * 32];
            bf16x8 bl = *(const bf16x8*)&prl[(nt * 16 + col) * 64 + q * 8 + ks * 32];
            acc2[nt] = __builtin_amdgcn_mfma_f32_16x16x32_bf16(ah, bh, acc2[nt], 0, 0, 0);
            acc2[nt] = __builtin_amdgcn_mfma_f32_16x16x32_bf16(ah, bl, acc2[nt], 0, 0, 0);
            acc2[nt] = __builtin_amdgcn_mfma_f32_16x16x32_bf16(al_, bh, acc2[nt], 0, 0, 0);
        }
    }
    float* oc = out + ((size_t)b * C_ + c) * PIX_;
#pragma unroll
    for (int nt = 0; nt < 4; nt++)
#pragma unroll
        for (int r = 0; r < 4; r++)
            oc[(i0 + q * 4 + r) * 64 + nt * 16 + col] = acc2[nt][r];
}

extern "C" void kernel_launch(void* const* d_in, const int* in_sizes, int n_in,
                              void* d_out, int out_size, void* d_ws, size_t ws_size,
                              hipStream_t stream) {
    const float* x = (const float*)d_in[0];
    const float* w1 = (const float*)d_in[1];
    const float* b1 = (const float*)d_in[2];
    const float* w2 = (const float*)d_in[3];
    const float* b2 = (const float*)d_in[4];
    const float* w_row = (const float*)d_in[5];
    const float* b_row = (const float*)d_in[6];
    const float* w_col = (const float*)d_in[7];
    const float* b_col = (const float*)d_in[8];
    float* out = (float*)d_out;

    char* ws = (char*)d_ws;
    u16* w1h = (u16*)(ws);                   //  65536 B
    u16* w1l = (u16*)(ws + 65536);           //  65536 B
    u16* w2h = (u16*)(ws + 131072);          //  131072 B
    u16* w2l = (u16*)(ws + 262144);          //  131072 B
    float* row_s = (float*)(ws + 393216);    //  8192 B
    float* col_s = (float*)(ws + 401408);    //  8192 B
    u16* prow_h = (u16*)(ws + 409600);       //  262144 B
    u16* prow_l = (u16*)(ws + 671744);       //  262144 B
    u16* pcol_h = (u16*)(ws + 933888);       //  262144 B
    u16* pcol_l = (u16*)(ws + 1196032);      //  262144 B

    hipLaunchKernelGGL(k0_init, dim3(8), dim3(256), 0, stream, row_s, col_s, b_row, b_col);
    hipLaunchKernelGGL(k_prep, dim3(384), dim3(256), 0, stream, w1, w2, w1h, w1l, w2h, w2l);
    hipLaunchKernelGGL(k12_fused, dim3(128, 32), dim3(256), 0, stream,
                       x, w1h, w1l, b1, w2h, w2l, b2, w_row, w_col, row_s, col_s);
    hipLaunchKernelGGL(k4_diffsort, dim3(64), dim3(256), 0, stream,
                       row_s, col_s, prow_h, prow_l, pcol_h, pcol_l);
    hipLaunchKernelGGL(k5_permute, dim3(128, 32), dim3(256), 0, stream,
                       x, pcol_h, pcol_l, prow_h, prow_l, out);
}

// Round 3
// 330.016 us; speedup vs baseline: 1.0858x; 1.0858x over previous
//
#include <hip/hip_runtime.h>
#include <math.h>

#define B_    32
#define C_    128
#define N_    64
#define HID_  256
#define PIX_  4096
#define STEEP 50.0f
#define INV_PI 0.318309886183790671f
#define LDH   272  // LDS row pitch (u16): 32 h1 chunks (256) + 16 pad; x tile time-shares cols 128..255
#define LDX   72   // k5 pitch

typedef unsigned short u16;
typedef __attribute__((ext_vector_type(8))) short bf16x8;
typedef __attribute__((ext_vector_type(4))) float f32x4;

__device__ __forceinline__ u16 f2bf(float f) {
    unsigned int u = __builtin_bit_cast(unsigned int, f);
    unsigned int r = (u + 0x7FFFu + ((u >> 16) & 1u)) >> 16;
    return (u16)r;
}
__device__ __forceinline__ float bf2f(u16 h) {
    unsigned int u = ((unsigned int)h) << 16;
    return __builtin_bit_cast(float, u);
}
// swizzled LDS indices (chunk = 8 u16 = 16 B, rotated by row for bank spread)
__device__ __forceinline__ int h1_idx(int p, int k) {
    return p * LDH + (((k >> 3) + (p & 7)) & 31) * 8 + (k & 7);
}
__device__ __forceinline__ int x_idx(int p, int k) {
    return p * LDH + 128 + (((k >> 3) + (p & 7)) & 15) * 8 + (k & 7);
}

// ---------------- K0: init col score buffer with bias ----------------
__global__ void k0_init(float* __restrict__ col_s, const float* __restrict__ b_col) {
    int i = blockIdx.x * 256 + threadIdx.x;
    if (i < B_ * N_) col_s[i] = b_col[0];
}

// ---------------- Kprep: decompose weights into bf16 hi/lo ----------------
__global__ void k_prep(const float* __restrict__ w1, const float* __restrict__ w2,
                       u16* __restrict__ w1h, u16* __restrict__ w1l,
                       u16* __restrict__ w2h, u16* __restrict__ w2l) {
    int i = blockIdx.x * 256 + threadIdx.x;
    if (i < HID_ * C_) {
        float v = w1[i];
        u16 h = f2bf(v);
        w1h[i] = h;
        w1l[i] = f2bf(v - bf2f(h));
    } else {
        int j = i - HID_ * C_;
        if (j < HID_ * HID_) {
            float v = w2[j];
            u16 h = f2bf(v);
            w2h[j] = h;
            w2l[j] = f2bf(v - bf2f(h));
        }
    }
}

// ---------------- K12: fused conv1+conv2+scores (R0 structure, 64-pixel tile) ----------------
// LDS 70144B -> 2 blocks/CU; VGPR headroom up to 256, so the extra xh/xl dump
// stores are free register-wise. Dump gives k5 bf16 hi/lo x without conversion.
__global__ __launch_bounds__(256) void k12_fused(
    const float* __restrict__ x,
    const u16* __restrict__ w1h, const u16* __restrict__ w1l,
    const float* __restrict__ b1,
    const u16* __restrict__ w2h, const u16* __restrict__ w2l,
    const float* __restrict__ b2, const float* __restrict__ w_row,
    const float* __restrict__ b_row, const float* __restrict__ w_col,
    float* __restrict__ row_s, float* __restrict__ col_s,
    u16* __restrict__ xh, u16* __restrict__ xl) {
    __shared__ __align__(16) u16 Lh[64 * LDH];   // 34816 B (h1 hi / x hi staging)
    __shared__ __align__(16) u16 Ll[64 * LDH];   // 34816 B (h1 lo / x lo staging)
    __shared__ float col_red[64];
    __shared__ float row_red;

    const int t = threadIdx.x;
    const int l = t & 63, w = t >> 6;
    const int col = l & 15, q = l >> 4;
    const int hrow = blockIdx.x;
    const int b = blockIdx.y;
    const float* xb = x + (size_t)b * C_ * PIX_ + hrow * 64;

    if (t < 64) col_red[t] = 0.f;
    if (t == 0) row_red = 0.f;

    // ---- stage FULL x tile [64 p][128 c] -> swizzled cols 128..255 (one barrier) ----
    // Also dump bf16 hi/lo of x to global [b][c][h][w] for k5 (no re-conversion there).
    {
        const int pt = t & 15, ct = t >> 4;      // ct 0..15
#pragma unroll
        for (int cc = 0; cc < 4; cc++) {
            const int c = cc * 32 + 2 * ct;
            float4 v0 = *(const float4*)&xb[(size_t)c * PIX_ + pt * 4];
            float4 v1 = *(const float4*)&xb[(size_t)(c + 1) * PIX_ + pt * 4];
            float a0[4] = {v0.x, v0.y, v0.z, v0.w};
            float a1[4] = {v1.x, v1.y, v1.z, v1.w};
            u16 sh0[4], sl0[4], sh1[4], sl1[4];
#pragma unroll
            for (int j = 0; j < 4; j++) {
                int p = pt * 4 + j;
                u16 h0 = f2bf(a0[j]), h1v = f2bf(a1[j]);
                u16 l0 = f2bf(a0[j] - bf2f(h0)), l1 = f2bf(a1[j] - bf2f(h1v));
                sh0[j] = h0; sl0[j] = l0; sh1[j] = h1v; sl1[j] = l1;
                int idx = x_idx(p, c);
                *(unsigned int*)&Lh[idx] = (unsigned int)h0 | ((unsigned int)h1v << 16);
                *(unsigned int*)&Ll[idx] = (unsigned int)l0 | ((unsigned int)l1 << 16);
            }
            if (xh) {
                size_t xo0 = ((size_t)b * C_ + c) * PIX_ + hrow * 64 + pt * 4;
                size_t xo1 = ((size_t)b * C_ + c + 1) * PIX_ + hrow * 64 + pt * 4;
                *(ushort4*)&xh[xo0] = (ushort4){sh0[0], sh0[1], sh0[2], sh0[3]};
                *(ushort4*)&xl[xo0] = (ushort4){sl0[0], sl0[1], sl0[2], sl0[3]};
                *(ushort4*)&xh[xo1] = (ushort4){sh1[0], sh1[1], sh1[2], sh1[3]};
                *(ushort4*)&xl[xo1] = (ushort4){sl1[0], sl1[1], sl1[2], sl1[3]};
            }
        }
    }
    __syncthreads();

    // ---- conv1: 192 MFMAs/wave, pipelined A (global) + B (LDS) ----
    f32x4 acc[4][4];
#pragma unroll
    for (int i = 0; i < 4; i++)
#pragma unroll
        for (int j = 0; j < 4; j++) acc[i][j] = (f32x4){0.f, 0.f, 0.f, 0.f};

    bf16x8 ah[4], al_[4];
#pragma unroll
    for (int mf = 0; mf < 4; mf++) {
        size_t ro = (size_t)(64 * w + 16 * mf + col) * C_ + q * 8;
        ah[mf] = *(const bf16x8*)&w1h[ro];
        al_[mf] = *(const bf16x8*)&w1l[ro];
    }
#pragma unroll
    for (int kc = 0; kc < 4; kc++) {
        bf16x8 bh[4], bl[4];
#pragma unroll
        for (int nt = 0; nt < 4; nt++) {
            int idx = x_idx(nt * 16 + col, kc * 32 + q * 8);
            bh[nt] = *(const bf16x8*)&Lh[idx];
            bl[nt] = *(const bf16x8*)&Ll[idx];
        }
        bf16x8 ahn[4], aln[4];
        const int kn = (kc + 1) & 3;
#pragma unroll
        for (int mf = 0; mf < 4; mf++) {
            size_t ro = (size_t)(64 * w + 16 * mf + col) * C_ + kn * 32 + q * 8;
            ahn[mf] = *(const bf16x8*)&w1h[ro];
            aln[mf] = *(const bf16x8*)&w1l[ro];
        }
#pragma unroll
        for (int mf = 0; mf < 4; mf++)
#pragma unroll
            for (int nt = 0; nt < 4; nt++) {
                acc[mf][nt] = __builtin_amdgcn_mfma_f32_16x16x32_bf16(ah[mf], bh[nt], acc[mf][nt], 0, 0, 0);
                acc[mf][nt] = __builtin_amdgcn_mfma_f32_16x16x32_bf16(ah[mf], bl[nt], acc[mf][nt], 0, 0, 0);
                acc[mf][nt] = __builtin_amdgcn_mfma_f32_16x16x32_bf16(al_[mf], bh[nt], acc[mf][nt], 0, 0, 0);
            }
#pragma unroll
        for (int mf = 0; mf < 4; mf++) { ah[mf] = ahn[mf]; al_[mf] = aln[mf]; }
    }

    // prefetch conv2's first A-frags before the barrier
    bf16x8 ah2[4], al2[4];
#pragma unroll
    for (int mf = 0; mf < 4; mf++) {
        size_t ro = (size_t)(64 * w + 16 * mf + col) * HID_ + q * 8;
        ah2[mf] = *(const bf16x8*)&w2h[ro];
        al2[mf] = *(const bf16x8*)&w2l[ro];
    }
    __syncthreads();   // all x-frag reads done; rows can be overwritten with h1

    // ---- conv1 epilogue: relu(acc+b1) -> swizzled h1 hi/lo ----
#pragma unroll
    for (int mf = 0; mf < 4; mf++) {
        int o = 64 * w + 16 * mf + q * 4;
        float bias[4];
#pragma unroll
        for (int r = 0; r < 4; r++) bias[r] = b1[o + r];
#pragma unroll
        for (int nt = 0; nt < 4; nt++) {
            int p = nt * 16 + col;
            u16 hh[4], ll[4];
#pragma unroll
            for (int r = 0; r < 4; r++) {
                float v = fmaxf(acc[mf][nt][r] + bias[r], 0.f);
                u16 h = f2bf(v);
                hh[r] = h;
                ll[r] = f2bf(v - bf2f(h));
            }
            int idx = h1_idx(p, o);
            *(unsigned long long*)&Lh[idx] =
                (unsigned long long)hh[0] | ((unsigned long long)hh[1] << 16) |
                ((unsigned long long)hh[2] << 32) | ((unsigned long long)hh[3] << 48);
            *(unsigned long long*)&Ll[idx] =
                (unsigned long long)ll[0] | ((unsigned long long)ll[1] << 16) |
                ((unsigned long long)ll[2] << 32) | ((unsigned long long)ll[3] << 48);
        }
    }
    __syncthreads();

    // ---- conv2: 384 MFMAs/wave, pipelined ----
    f32x4 acc2[4][4];
#pragma unroll
    for (int i = 0; i < 4; i++)
#pragma unroll
        for (int j = 0; j < 4; j++) acc2[i][j] = (f32x4){0.f, 0.f, 0.f, 0.f};

#pragma unroll
    for (int kc = 0; kc < 8; kc++) {
        bf16x8 bh[4], bl[4];
#pragma unroll
        for (int nt = 0; nt < 4; nt++) {
            int idx = h1_idx(nt * 16 + col, kc * 32 + q * 8);
            bh[nt] = *(const bf16x8*)&Lh[idx];
            bl[nt] = *(const bf16x8*)&Ll[idx];
        }
        bf16x8 ahn[4], aln[4];
        const int kn = (kc + 1) & 7;
#pragma unroll
        for (int mf = 0; mf < 4; mf++) {
            size_t ro = (size_t)(64 * w + 16 * mf + col) * HID_ + kn * 32 + q * 8;
            ahn[mf] = *(const bf16x8*)&w2h[ro];
            aln[mf] = *(const bf16x8*)&w2l[ro];
        }
#pragma unroll
        for (int mf = 0; mf < 4; mf++)
#pragma unroll
            for (int nt = 0; nt < 4; nt++) {
                acc2[mf][nt] = __builtin_amdgcn_mfma_f32_16x16x32_bf16(ah2[mf], bh[nt], acc2[mf][nt], 0, 0, 0);
                acc2[mf][nt] = __builtin_amdgcn_mfma_f32_16x16x32_bf16(ah2[mf], bl[nt], acc2[mf][nt], 0, 0, 0);
                acc2[mf][nt] = __builtin_amdgcn_mfma_f32_16x16x32_bf16(al2[mf], bh[nt], acc2[mf][nt], 0, 0, 0);
            }
#pragma unroll
        for (int mf = 0; mf < 4; mf++) { ah2[mf] = ahn[mf]; al2[mf] = aln[mf]; }
    }

    // ---- score epilogue ----
    float rpart = 0.f;
    float cpart[4] = {0.f, 0.f, 0.f, 0.f};
#pragma unroll
    for (int mf = 0; mf < 4; mf++) {
        int o = 64 * w + 16 * mf + q * 4;
#pragma unroll
        for (int r = 0; r < 4; r++) {
            float bias = b2[o + r];
            float wcv = w_col[(o + r) * N_ + hrow];
#pragma unroll
            for (int nt = 0; nt < 4; nt++) {
                int wc = nt * 16 + col;
                float v = fmaxf(acc2[mf][nt][r] + bias, 0.f);
                rpart += v * w_row[(o + r) * N_ + wc];
                cpart[nt] += v * wcv;
            }
        }
    }
#pragma unroll
    for (int off = 32; off; off >>= 1) rpart += __shfl_xor(rpart, off, 64);
    if (l == 0) atomicAdd(&row_red, rpart);
#pragma unroll
    for (int nt = 0; nt < 4; nt++) {
        float cp = cpart[nt];
        cp += __shfl_xor(cp, 16, 64);
        cp += __shfl_xor(cp, 32, 64);
        if (l < 16) atomicAdd(&col_red[nt * 16 + l], cp);
    }
    __syncthreads();
    if (t < 64) atomicAdd(&col_s[b * N_ + t], col_red[t]);
    if (t == 0) row_s[b * N_ + hrow] = b_row[0] + row_red;
}

// ---------------- K4: diff bitonic sort, register-resident P, shuffle-only ----------------
__global__ __launch_bounds__(256) void k4_diffsort(const float* __restrict__ row_s,
                                                   const float* __restrict__ col_s,
                                                   u16* __restrict__ prow_h, u16* __restrict__ prow_l,
                                                   u16* __restrict__ pcol_h, u16* __restrict__ pcol_l) {
    const int t = threadIdx.x;
    const int lane = t & 63, w = t >> 6;
    const int which = blockIdx.x & 1;
    const int b = blockIdx.x >> 1;
    const float* sc = which ? col_s : row_s;
    u16* Ph = which ? pcol_h : prow_h;
    u16* Pl = which ? pcol_l : prow_l;

    float xv = sc[b * 64 + lane];
    float P[16];
#pragma unroll
    for (int r = 0; r < 16; r++) P[r] = ((w * 16 + r) == lane) ? 1.f : 0.f;

#pragma unroll
    for (int bl = 0; bl < 6; bl++) {
#pragma unroll
        for (int ly = 0; ly <= bl; ly++) {
            const int sh = bl - ly;
            const int m = 1 << sh;
            float xp = __shfl_xor(xv, m, 64);
            int lower = ((lane >> sh) & 1) ^ 1;            // lane is the low member of its pair
            int swp = (lane >> (bl + 1)) & 1;              // direction flip for this pair
            float diff = (lower ^ swp) ? (xp - xv) : (xv - xp);   // xb - xa (same value both lanes)
            float al = atanf(diff * STEEP) * INV_PI + 0.5f;
            xv = al * xv + (1.f - al) * xp;
#pragma unroll
            for (int r = 0; r < 16; r++) {
                float Pp = __shfl_xor(P[r], m, 64);
                P[r] = al * P[r] + (1.f - al) * Pp;
            }
        }
    }
#pragma unroll
    for (int r = 0; r < 16; r++) {
        float v = P[r];
        u16 h = f2bf(v);
        int row = w * 16 + r;
        Ph[(size_t)b * 4096 + row * 64 + lane] = h;
        Pl[(size_t)b * 4096 + row * 64 + lane] = f2bf(v - bf2f(h));
    }
}

// ---------------- K5 (fast): double permutation, x read as bf16 frags from global ----------------
// No x staging, no conversion, ZERO barriers (Z tile is wave-private).
// LDS 18432B -> 8 blocks/CU.
__global__ __launch_bounds__(256) void k5_direct(const u16* __restrict__ xh,
                                                 const u16* __restrict__ xl,
                                                 const u16* __restrict__ pcol_h,
                                                 const u16* __restrict__ pcol_l,
                                                 const u16* __restrict__ prow_h,
                                                 const u16* __restrict__ prow_l,
                                                 float* __restrict__ out) {
    __shared__ __align__(16) u16 Zh[64 * LDX];
    __shared__ __align__(16) u16 Zl[64 * LDX];
    const int t = threadIdx.x;
    const int l = t & 63, w = t >> 6;
    const int col = l & 15, q = l >> 4;
    const int b = blockIdx.y;
    const int c = blockIdx.x;
    const int i0 = w * 16;

    const u16* pch = pcol_h + (size_t)b * 4096;
    const u16* pcl = pcol_l + (size_t)b * 4096;
    const u16* prh = prow_h + (size_t)b * 4096;
    const u16* prl = prow_l + (size_t)b * 4096;
    const u16* xch = xh + ((size_t)b * C_ + c) * PIX_;
    const u16* xcl = xl + ((size_t)b * C_ + c) * PIX_;

    bf16x8 pcA_h[2], pcA_l[2];
#pragma unroll
    for (int ks = 0; ks < 2; ks++) {
        pcA_h[ks] = *(const bf16x8*)&pch[(i0 + col) * 64 + q * 8 + ks * 32];
        pcA_l[ks] = *(const bf16x8*)&pcl[(i0 + col) * 64 + q * 8 + ks * 32];
    }

    f32x4 acc[4];
#pragma unroll
    for (int nt = 0; nt < 4; nt++) acc[nt] = (f32x4){0.f, 0.f, 0.f, 0.f};
#pragma unroll
    for (int ks = 0; ks < 2; ks++) {
        bf16x8 ah = pcA_h[ks], al_ = pcA_l[ks];
#pragma unroll
        for (int nt = 0; nt < 4; nt++) {
            bf16x8 bh = *(const bf16x8*)&xch[(nt * 16 + col) * 64 + q * 8 + ks * 32];
            bf16x8 bl = *(const bf16x8*)&xcl[(nt * 16 + col) * 64 + q * 8 + ks * 32];
            acc[nt] = __builtin_amdgcn_mfma_f32_16x16x32_bf16(ah, bh, acc[nt], 0, 0, 0);
            acc[nt] = __builtin_amdgcn_mfma_f32_16x16x32_bf16(ah, bl, acc[nt], 0, 0, 0);
            acc[nt] = __builtin_amdgcn_mfma_f32_16x16x32_bf16(al_, bh, acc[nt], 0, 0, 0);
        }
    }
    // Z tiles are wave-private (wave w writes rows i0..i0+15, reads the same);
    // compiler inserts the lgkm wait; no barrier needed (validated in R2).
#pragma unroll
    for (int nt = 0; nt < 4; nt++)
#pragma unroll
        for (int r = 0; r < 4; r++) {
            float v = acc[nt][r];
            u16 h = f2bf(v);
            int rw = i0 + q * 4 + r;
            Zh[rw * LDX + nt * 16 + col] = h;
            Zl[rw * LDX + nt * 16 + col] = f2bf(v - bf2f(h));
        }

    f32x4 acc2[4];
#pragma unroll
    for (int nt = 0; nt < 4; nt++) acc2[nt] = (f32x4){0.f, 0.f, 0.f, 0.f};
#pragma unroll
    for (int ks = 0; ks < 2; ks++) {
        bf16x8 ah = *(const bf16x8*)&Zh[(i0 + col) * LDX + q * 8 + ks * 32];
        bf16x8 al_ = *(const bf16x8*)&Zl[(i0 + col) * LDX + q * 8 + ks * 32];
#pragma unroll
        for (int nt = 0; nt < 4; nt++) {
            bf16x8 bh = *(const bf16x8*)&prh[(nt * 16 + col) * 64 + q * 8 + ks * 32];
            bf16x8 bl = *(const bf16x8*)&prl[(nt * 16 + col) * 64 + q * 8 + ks * 32];
            acc2[nt] = __builtin_amdgcn_mfma_f32_16x16x32_bf16(ah, bh, acc2[nt], 0, 0, 0);
            acc2[nt] = __builtin_amdgcn_mfma_f32_16x16x32_bf16(ah, bl, acc2[nt], 0, 0, 0);
            acc2[nt] = __builtin_amdgcn_mfma_f32_16x16x32_bf16(al_, bh, acc2[nt], 0, 0, 0);
        }
    }
    float* oc = out + ((size_t)b * C_ + c) * PIX_;
#pragma unroll
    for (int nt = 0; nt < 4; nt++)
#pragma unroll
        for (int r = 0; r < 4; r++)
            oc[(i0 + q * 4 + r) * 64 + nt * 16 + col] = acc2[nt][r];
}

// ---------------- K5 (fallback, R0 version): used when workspace too small ----------------
__global__ __launch_bounds__(256) void k5_permute(const float* __restrict__ x,
                                                  const u16* __restrict__ pcol_h,
                                                  const u16* __restrict__ pcol_l,
                                                  const u16* __restrict__ prow_h,
                                                  const u16* __restrict__ prow_l,
                                                  float* __restrict__ out) {
    __shared__ __align__(16) u16 Xh[64 * LDX];
    __shared__ __align__(16) u16 Xl[64 * LDX];
    __shared__ __align__(16) u16 Zh[64 * LDX];
    __shared__ __align__(16) u16 Zl[64 * LDX];
    const int t = threadIdx.x;
    const int l = t & 63, w = t >> 6;
    const int col = l & 15, q = l >> 4;
    const int b = blockIdx.y;
    const int cbase = blockIdx.x * 4;
    const int i0 = w * 16;

    const u16* pch = pcol_h + (size_t)b * 4096;
    const u16* pcl = pcol_l + (size_t)b * 4096;
    const u16* prh = prow_h + (size_t)b * 4096;
    const u16* prl = prow_l + (size_t)b * 4096;

    bf16x8 pcA_h[2], pcA_l[2];
#pragma unroll
    for (int ks = 0; ks < 2; ks++) {
        pcA_h[ks] = *(const bf16x8*)&pch[(i0 + col) * 64 + q * 8 + ks * 32];
        pcA_l[ks] = *(const bf16x8*)&pcl[(i0 + col) * 64 + q * 8 + ks * 32];
    }

    for (int ci = 0; ci < 4; ci++) {
        const int c = cbase + ci;
        const float* xc = x + ((size_t)b * C_ + c) * PIX_;
#pragma unroll
        for (int k = 0; k < 4; k++) {
            int f = t + k * 256;
            int rw = f >> 4, c4 = f & 15;
            float4 v = *(const float4*)&xc[f * 4];
            u16 h0 = f2bf(v.x), h1 = f2bf(v.y), h2 = f2bf(v.z), h3 = f2bf(v.w);
            ushort4 hv = {h0, h1, h2, h3};
            ushort4 lv = {f2bf(v.x - bf2f(h0)), f2bf(v.y - bf2f(h1)),
                          f2bf(v.z - bf2f(h2)), f2bf(v.w - bf2f(h3))};
            *(ushort4*)&Xh[rw * LDX + c4 * 4] = hv;
            *(ushort4*)&Xl[rw * LDX + c4 * 4] = lv;
        }
        __syncthreads();

        f32x4 acc[4];
#pragma unroll
        for (int nt = 0; nt < 4; nt++) acc[nt] = (f32x4){0.f, 0.f, 0.f, 0.f};
#pragma unroll
        for (int ks = 0; ks < 2; ks++) {
            bf16x8 ah = pcA_h[ks], al_ = pcA_l[ks];
#pragma unroll
            for (int nt = 0; nt < 4; nt++) {
                bf16x8 bh = *(const bf16x8*)&Xh[(nt * 16 + col) * LDX + q * 8 + ks * 32];
                bf16x8 bl = *(const bf16x8*)&Xl[(nt * 16 + col) * LDX + q * 8 + ks * 32];
                acc[nt] = __builtin_amdgcn_mfma_f32_16x16x32_bf16(ah, bh, acc[nt], 0, 0, 0);
                acc[nt] = __builtin_amdgcn_mfma_f32_16x16x32_bf16(ah, bl, acc[nt], 0, 0, 0);
                acc[nt] = __builtin_amdgcn_mfma_f32_16x16x32_bf16(al_, bh, acc[nt], 0, 0, 0);
            }
        }
#pragma unroll
        for (int nt = 0; nt < 4; nt++)
#pragma unroll
            for (int r = 0; r < 4; r++) {
                float v = acc[nt][r];
                u16 h = f2bf(v);
                int rw = i0 + q * 4 + r;
                Zh[rw * LDX + nt * 16 + col] = h;
                Zl[rw * LDX + nt * 16 + col] = f2bf(v - bf2f(h));
            }

        f32x4 acc2[4];
#pragma unroll
        for (int nt = 0; nt < 4; nt++) acc2[nt] = (f32x4){0.f, 0.f, 0.f, 0.f};
#pragma unroll
        for (int ks = 0; ks < 2; ks++) {
            bf16x8 ah = *(const bf16x8*)&Zh[(i0 + col) * LDX + q * 8 + ks * 32];
            bf16x8 al_ = *(const bf16x8*)&Zl[(i0 + col) * LDX + q * 8 + ks * 32];
#pragma unroll
            for (int nt = 0; nt < 4; nt++) {
                bf16x8 bh = *(const bf16x8*)&prh[(nt * 16 + col) * 64 + q * 8 + ks * 32];
                bf16x8 bl = *(const bf16x8*)&prl[(nt * 16 + col) * 64 + q * 8 + ks * 32];
                acc2[nt] = __builtin_amdgcn_mfma_f32_16x16x32_bf16(ah, bh, acc2[nt], 0, 0, 0);
                acc2[nt] = __builtin_amdgcn_mfma_f32_16x16x32_bf16(ah, bl, acc2[nt], 0, 0, 0);
                acc2[nt] = __builtin_amdgcn_mfma_f32_16x16x32_bf16(al_, bh, acc2[nt], 0, 0, 0);
            }
        }
        float* oc = out + ((size_t)b * C_ + c) * PIX_;
#pragma unroll
        for (int nt = 0; nt < 4; nt++)
#pragma unroll
            for (int r = 0; r < 4; r++)
                oc[(i0 + q * 4 + r) * 64 + nt * 16 + col] = acc2[nt][r];
        __syncthreads();
    }
}

extern "C" void kernel_launch(void* const* d_in, const int* in_sizes, int n_in,
                              void* d_out, int out_size, void* d_ws, size_t ws_size,
                              hipStream_t stream) {
    const float* x = (const float*)d_in[0];
    const float* w1 = (const float*)d_in[1];
    const float* b1 = (const float*)d_in[2];
    const float* w2 = (const float*)d_in[3];
    const float* b2 = (const float*)d_in[4];
    const float* w_row = (const float*)d_in[5];
    const float* b_row = (const float*)d_in[6];
    const float* w_col = (const float*)d_in[7];
    const float* b_col = (const float*)d_in[8];
    float* out = (float*)d_out;

    char* ws = (char*)d_ws;
    u16* w1h = (u16*)(ws);                   //  65536 B
    u16* w1l = (u16*)(ws + 65536);           //  65536 B
    u16* w2h = (u16*)(ws + 131072);          //  131072 B
    u16* w2l = (u16*)(ws + 262144);          //  131072 B
    float* row_s = (float*)(ws + 393216);    //  8192 B
    float* col_s = (float*)(ws + 401408);    //  8192 B
    u16* prow_h = (u16*)(ws + 409600);       //  262144 B
    u16* prow_l = (u16*)(ws + 671744);       //  262144 B
    u16* pcol_h = (u16*)(ws + 933888);       //  262144 B
    u16* pcol_l = (u16*)(ws + 1196032);      //  262144 B
    // bf16 hi/lo dump of x for k5_direct:
    u16* xh = (u16*)(ws + 1458176);          //  33554432 B
    u16* xl = (u16*)(ws + 35012608);         //  33554432 B
    const size_t WS_NEED = 35012608ULL + 33554432ULL;  // 68567040
    const bool fast = ws_size >= WS_NEED;

    hipLaunchKernelGGL(k0_init, dim3(8), dim3(256), 0, stream, col_s, b_col);
    hipLaunchKernelGGL(k_prep, dim3(384), dim3(256), 0, stream, w1, w2, w1h, w1l, w2h, w2l);
    hipLaunchKernelGGL(k12_fused, dim3(64, 32), dim3(256), 0, stream,
                       x, w1h, w1l, b1, w2h, w2l, b2, w_row, b_row, w_col, row_s, col_s,
                       fast ? xh : (u16*)nullptr, fast ? xl : (u16*)nullptr);
    hipLaunchKernelGGL(k4_diffsort, dim3(64), dim3(256), 0, stream,
                       row_s, col_s, prow_h, prow_l, pcol_h, pcol_l);
    if (fast) {
        hipLaunchKernelGGL(k5_direct, dim3(128, 32), dim3(256), 0, stream,
                           xh, xl, pcol_h, pcol_l, prow_h, prow_l, out);
    } else {
        hipLaunchKernelGGL(k5_permute, dim3(32, 32), dim3(256), 0, stream,
                           x, pcol_h, pcol_l, prow_h, prow_l, out);
    }
}

// Round 4
// 275.897 us; speedup vs baseline: 1.2988x; 1.1962x over previous
//
#include <hip/hip_runtime.h>
#include <math.h>

#define B_    32
#define C_    128
#define N_    64
#define HID_  256
#define PIX_  4096
#define STEEP 50.0f
#define INV_PI 0.318309886183790671f
#define LDH   272  // LDS row pitch (u16): 32 h1 chunks (256) + 16 pad; x tile time-shares cols 128..255
#define LDX   72   // k5 pitch

typedef unsigned short u16;
typedef __attribute__((ext_vector_type(8))) short bf16x8;
typedef __attribute__((ext_vector_type(4))) float f32x4;

__device__ __forceinline__ u16 f2bf(float f) {
    unsigned int u = __builtin_bit_cast(unsigned int, f);
    unsigned int r = (u + 0x7FFFu + ((u >> 16) & 1u)) >> 16;
    return (u16)r;
}
__device__ __forceinline__ float bf2f(u16 h) {
    unsigned int u = ((unsigned int)h) << 16;
    return __builtin_bit_cast(float, u);
}
// swizzled LDS indices (chunk = 8 u16 = 16 B, rotated by row for bank spread)
__device__ __forceinline__ int h1_idx(int p, int k) {
    return p * LDH + (((k >> 3) + (p & 7)) & 31) * 8 + (k & 7);
}
__device__ __forceinline__ int x_idx(int p, int k) {
    return p * LDH + 128 + (((k >> 3) + (p & 7)) & 15) * 8 + (k & 7);
}

// ---------------- Kprep: decompose weights into bf16 hi/lo + init col_s ----------------
__global__ void k_prep(const float* __restrict__ w1, const float* __restrict__ w2,
                       u16* __restrict__ w1h, u16* __restrict__ w1l,
                       u16* __restrict__ w2h, u16* __restrict__ w2l,
                       float* __restrict__ col_s, const float* __restrict__ b_col) {
    int i = blockIdx.x * 256 + threadIdx.x;
    if (i < B_ * N_) col_s[i] = b_col[0];
    if (i < HID_ * C_) {
        float v = w1[i];
        u16 h = f2bf(v);
        w1h[i] = h;
        w1l[i] = f2bf(v - bf2f(h));
    } else {
        int j = i - HID_ * C_;
        if (j < HID_ * HID_) {
            float v = w2[j];
            u16 h = f2bf(v);
            w2h[j] = h;
            w2l[j] = f2bf(v - bf2f(h));
        }
    }
}

// ---------------- K12: fused conv1+conv2+scores (R0 body, 64-pixel tile) ----------------
__global__ __launch_bounds__(256) void k12_fused(
    const float* __restrict__ x,
    const u16* __restrict__ w1h, const u16* __restrict__ w1l,
    const float* __restrict__ b1,
    const u16* __restrict__ w2h, const u16* __restrict__ w2l,
    const float* __restrict__ b2, const float* __restrict__ w_row,
    const float* __restrict__ b_row, const float* __restrict__ w_col,
    float* __restrict__ row_s, float* __restrict__ col_s) {
    __shared__ __align__(16) u16 Lh[64 * LDH];   // 34816 B (h1 hi / x hi staging)
    __shared__ __align__(16) u16 Ll[64 * LDH];   // 34816 B (h1 lo / x lo staging)
    __shared__ float col_red[64];
    __shared__ float row_red;

    const int t = threadIdx.x;
    const int l = t & 63, w = t >> 6;
    const int col = l & 15, q = l >> 4;
    const int hrow = blockIdx.x;
    const int b = blockIdx.y;
    const float* xb = x + (size_t)b * C_ * PIX_ + hrow * 64;

    if (t < 64) col_red[t] = 0.f;
    if (t == 0) row_red = 0.f;

    // ---- stage FULL x tile [64 p][128 c] -> swizzled cols 128..255 (one barrier) ----
    {
        const int pt = t & 15, ct = t >> 4;      // ct 0..15
#pragma unroll
        for (int cc = 0; cc < 4; cc++) {
            const int c = cc * 32 + 2 * ct;
            float4 v0 = *(const float4*)&xb[(size_t)c * PIX_ + pt * 4];
            float4 v1 = *(const float4*)&xb[(size_t)(c + 1) * PIX_ + pt * 4];
            float a0[4] = {v0.x, v0.y, v0.z, v0.w};
            float a1[4] = {v1.x, v1.y, v1.z, v1.w};
#pragma unroll
            for (int j = 0; j < 4; j++) {
                int p = pt * 4 + j;
                u16 h0 = f2bf(a0[j]), h1v = f2bf(a1[j]);
                u16 l0 = f2bf(a0[j] - bf2f(h0)), l1 = f2bf(a1[j] - bf2f(h1v));
                int idx = x_idx(p, c);
                *(unsigned int*)&Lh[idx] = (unsigned int)h0 | ((unsigned int)h1v << 16);
                *(unsigned int*)&Ll[idx] = (unsigned int)l0 | ((unsigned int)l1 << 16);
            }
        }
    }
    __syncthreads();

    // ---- conv1: 192 MFMAs/wave, pipelined A (global) + B (LDS) ----
    f32x4 acc[4][4];
#pragma unroll
    for (int i = 0; i < 4; i++)
#pragma unroll
        for (int j = 0; j < 4; j++) acc[i][j] = (f32x4){0.f, 0.f, 0.f, 0.f};

    bf16x8 ah[4], al_[4];
#pragma unroll
    for (int mf = 0; mf < 4; mf++) {
        size_t ro = (size_t)(64 * w + 16 * mf + col) * C_ + q * 8;
        ah[mf] = *(const bf16x8*)&w1h[ro];
        al_[mf] = *(const bf16x8*)&w1l[ro];
    }
#pragma unroll
    for (int kc = 0; kc < 4; kc++) {
        bf16x8 bh[4], bl[4];
#pragma unroll
        for (int nt = 0; nt < 4; nt++) {
            int idx = x_idx(nt * 16 + col, kc * 32 + q * 8);
            bh[nt] = *(const bf16x8*)&Lh[idx];
            bl[nt] = *(const bf16x8*)&Ll[idx];
        }
        bf16x8 ahn[4], aln[4];
        const int kn = (kc + 1) & 3;
#pragma unroll
        for (int mf = 0; mf < 4; mf++) {
            size_t ro = (size_t)(64 * w + 16 * mf + col) * C_ + kn * 32 + q * 8;
            ahn[mf] = *(const bf16x8*)&w1h[ro];
            aln[mf] = *(const bf16x8*)&w1l[ro];
        }
#pragma unroll
        for (int mf = 0; mf < 4; mf++)
#pragma unroll
            for (int nt = 0; nt < 4; nt++) {
                acc[mf][nt] = __builtin_amdgcn_mfma_f32_16x16x32_bf16(ah[mf], bh[nt], acc[mf][nt], 0, 0, 0);
                acc[mf][nt] = __builtin_amdgcn_mfma_f32_16x16x32_bf16(ah[mf], bl[nt], acc[mf][nt], 0, 0, 0);
                acc[mf][nt] = __builtin_amdgcn_mfma_f32_16x16x32_bf16(al_[mf], bh[nt], acc[mf][nt], 0, 0, 0);
            }
#pragma unroll
        for (int mf = 0; mf < 4; mf++) { ah[mf] = ahn[mf]; al_[mf] = aln[mf]; }
    }

    // prefetch conv2's first A-frags before the barrier
    bf16x8 ah2[4], al2[4];
#pragma unroll
    for (int mf = 0; mf < 4; mf++) {
        size_t ro = (size_t)(64 * w + 16 * mf + col) * HID_ + q * 8;
        ah2[mf] = *(const bf16x8*)&w2h[ro];
        al2[mf] = *(const bf16x8*)&w2l[ro];
    }
    __syncthreads();   // all x-frag reads done; rows can be overwritten with h1

    // ---- conv1 epilogue: relu(acc+b1) -> swizzled h1 hi/lo ----
#pragma unroll
    for (int mf = 0; mf < 4; mf++) {
        int o = 64 * w + 16 * mf + q * 4;
        float bias[4];
#pragma unroll
        for (int r = 0; r < 4; r++) bias[r] = b1[o + r];
#pragma unroll
        for (int nt = 0; nt < 4; nt++) {
            int p = nt * 16 + col;
            u16 hh[4], ll[4];
#pragma unroll
            for (int r = 0; r < 4; r++) {
                float v = fmaxf(acc[mf][nt][r] + bias[r], 0.f);
                u16 h = f2bf(v);
                hh[r] = h;
                ll[r] = f2bf(v - bf2f(h));
            }
            int idx = h1_idx(p, o);
            *(unsigned long long*)&Lh[idx] =
                (unsigned long long)hh[0] | ((unsigned long long)hh[1] << 16) |
                ((unsigned long long)hh[2] << 32) | ((unsigned long long)hh[3] << 48);
            *(unsigned long long*)&Ll[idx] =
                (unsigned long long)ll[0] | ((unsigned long long)ll[1] << 16) |
                ((unsigned long long)ll[2] << 32) | ((unsigned long long)ll[3] << 48);
        }
    }
    __syncthreads();

    // ---- conv2: 384 MFMAs/wave, pipelined ----
    f32x4 acc2[4][4];
#pragma unroll
    for (int i = 0; i < 4; i++)
#pragma unroll
        for (int j = 0; j < 4; j++) acc2[i][j] = (f32x4){0.f, 0.f, 0.f, 0.f};

#pragma unroll
    for (int kc = 0; kc < 8; kc++) {
        bf16x8 bh[4], bl[4];
#pragma unroll
        for (int nt = 0; nt < 4; nt++) {
            int idx = h1_idx(nt * 16 + col, kc * 32 + q * 8);
            bh[nt] = *(const bf16x8*)&Lh[idx];
            bl[nt] = *(const bf16x8*)&Ll[idx];
        }
        bf16x8 ahn[4], aln[4];
        const int kn = (kc + 1) & 7;
#pragma unroll
        for (int mf = 0; mf < 4; mf++) {
            size_t ro = (size_t)(64 * w + 16 * mf + col) * HID_ + kn * 32 + q * 8;
            ahn[mf] = *(const bf16x8*)&w2h[ro];
            aln[mf] = *(const bf16x8*)&w2l[ro];
        }
#pragma unroll
        for (int mf = 0; mf < 4; mf++)
#pragma unroll
            for (int nt = 0; nt < 4; nt++) {
                acc2[mf][nt] = __builtin_amdgcn_mfma_f32_16x16x32_bf16(ah2[mf], bh[nt], acc2[mf][nt], 0, 0, 0);
                acc2[mf][nt] = __builtin_amdgcn_mfma_f32_16x16x32_bf16(ah2[mf], bl[nt], acc2[mf][nt], 0, 0, 0);
                acc2[mf][nt] = __builtin_amdgcn_mfma_f32_16x16x32_bf16(al2[mf], bh[nt], acc2[mf][nt], 0, 0, 0);
            }
#pragma unroll
        for (int mf = 0; mf < 4; mf++) { ah2[mf] = ahn[mf]; al2[mf] = aln[mf]; }
    }

    // ---- score epilogue ----
    float rpart = 0.f;
    float cpart[4] = {0.f, 0.f, 0.f, 0.f};
#pragma unroll
    for (int mf = 0; mf < 4; mf++) {
        int o = 64 * w + 16 * mf + q * 4;
#pragma unroll
        for (int r = 0; r < 4; r++) {
            float bias = b2[o + r];
            float wcv = w_col[(o + r) * N_ + hrow];
#pragma unroll
            for (int nt = 0; nt < 4; nt++) {
                int wc = nt * 16 + col;
                float v = fmaxf(acc2[mf][nt][r] + bias, 0.f);
                rpart += v * w_row[(o + r) * N_ + wc];
                cpart[nt] += v * wcv;
            }
        }
    }
#pragma unroll
    for (int off = 32; off; off >>= 1) rpart += __shfl_xor(rpart, off, 64);
    if (l == 0) atomicAdd(&row_red, rpart);
#pragma unroll
    for (int nt = 0; nt < 4; nt++) {
        float cp = cpart[nt];
        cp += __shfl_xor(cp, 16, 64);
        cp += __shfl_xor(cp, 32, 64);
        if (l < 16) atomicAdd(&col_red[nt * 16 + l], cp);
    }
    __syncthreads();
    if (t < 64) atomicAdd(&col_s[b * N_ + t], col_red[t]);
    if (t == 0) row_s[b * N_ + hrow] = b_row[0] + row_red;
}

// ---------------- K4: diff bitonic sort, register-resident P, shuffle-only ----------------
__global__ __launch_bounds__(256) void k4_diffsort(const float* __restrict__ row_s,
                                                   const float* __restrict__ col_s,
                                                   u16* __restrict__ prow_h, u16* __restrict__ prow_l,
                                                   u16* __restrict__ pcol_h, u16* __restrict__ pcol_l) {
    const int t = threadIdx.x;
    const int lane = t & 63, w = t >> 6;
    const int which = blockIdx.x & 1;
    const int b = blockIdx.x >> 1;
    const float* sc = which ? col_s : row_s;
    u16* Ph = which ? pcol_h : prow_h;
    u16* Pl = which ? pcol_l : prow_l;

    float xv = sc[b * 64 + lane];
    float P[16];
#pragma unroll
    for (int r = 0; r < 16; r++) P[r] = ((w * 16 + r) == lane) ? 1.f : 0.f;

#pragma unroll
    for (int bl = 0; bl < 6; bl++) {
#pragma unroll
        for (int ly = 0; ly <= bl; ly++) {
            const int sh = bl - ly;
            const int m = 1 << sh;
            float xp = __shfl_xor(xv, m, 64);
            int lower = ((lane >> sh) & 1) ^ 1;            // lane is the low member of its pair
            int swp = (lane >> (bl + 1)) & 1;              // direction flip for this pair
            float diff = (lower ^ swp) ? (xp - xv) : (xv - xp);   // xb - xa (same value both lanes)
            float al = atanf(diff * STEEP) * INV_PI + 0.5f;
            xv = al * xv + (1.f - al) * xp;
#pragma unroll
            for (int r = 0; r < 16; r++) {
                float Pp = __shfl_xor(P[r], m, 64);
                P[r] = al * P[r] + (1.f - al) * Pp;
            }
        }
    }
#pragma unroll
    for (int r = 0; r < 16; r++) {
        float v = P[r];
        u16 h = f2bf(v);
        int row = w * 16 + r;
        Ph[(size_t)b * 4096 + row * 64 + lane] = h;
        Pl[(size_t)b * 4096 + row * 64 + lane] = f2bf(v - bf2f(h));
    }
}

// ---------------- K5: fused double permutation via MFMA, serial-4 channels + T14 ----------------
// Structure = R0's (best measured). T14 async-STAGE: next channel's float4 loads
// issue right after the post-staging barrier so HBM latency hides under the
// current channel's MFMAs; convert+LDS-write happens at the top of the next iter.
__global__ __launch_bounds__(256) void k5_permute(const float* __restrict__ x,
                                                  const u16* __restrict__ pcol_h,
                                                  const u16* __restrict__ pcol_l,
                                                  const u16* __restrict__ prow_h,
                                                  const u16* __restrict__ prow_l,
                                                  float* __restrict__ out) {
    __shared__ __align__(16) u16 Xh[64 * LDX];
    __shared__ __align__(16) u16 Xl[64 * LDX];
    __shared__ __align__(16) u16 Zh[64 * LDX];
    __shared__ __align__(16) u16 Zl[64 * LDX];
    const int t = threadIdx.x;
    const int l = t & 63, w = t >> 6;
    const int col = l & 15, q = l >> 4;
    const int b = blockIdx.y;
    const int cbase = blockIdx.x * 4;
    const int i0 = w * 16;

    const u16* pch = pcol_h + (size_t)b * 4096;
    const u16* pcl = pcol_l + (size_t)b * 4096;
    const u16* prh = prow_h + (size_t)b * 4096;
    const u16* prl = prow_l + (size_t)b * 4096;

    bf16x8 pcA_h[2], pcA_l[2];
#pragma unroll
    for (int ks = 0; ks < 2; ks++) {
        pcA_h[ks] = *(const bf16x8*)&pch[(i0 + col) * 64 + q * 8 + ks * 32];
        pcA_l[ks] = *(const bf16x8*)&pcl[(i0 + col) * 64 + q * 8 + ks * 32];
    }

    // prologue: channel 0 into registers
    float4 pv[4];
    {
        const float* xc0 = x + ((size_t)b * C_ + cbase) * PIX_;
#pragma unroll
        for (int k = 0; k < 4; k++) pv[k] = *(const float4*)&xc0[(t + k * 256) * 4];
    }

    for (int ci = 0; ci < 4; ci++) {
        // ---- convert + stage current channel's registers into LDS ----
#pragma unroll
        for (int k = 0; k < 4; k++) {
            int f = t + k * 256;
            int rw = f >> 4, c4 = f & 15;
            float4 v = pv[k];
            u16 h0 = f2bf(v.x), h1 = f2bf(v.y), h2 = f2bf(v.z), h3 = f2bf(v.w);
            ushort4 hv = {h0, h1, h2, h3};
            ushort4 lv = {f2bf(v.x - bf2f(h0)), f2bf(v.y - bf2f(h1)),
                          f2bf(v.z - bf2f(h2)), f2bf(v.w - bf2f(h3))};
            *(ushort4*)&Xh[rw * LDX + c4 * 4] = hv;
            *(ushort4*)&Xl[rw * LDX + c4 * 4] = lv;
        }
        __syncthreads();

        // ---- T14: issue NEXT channel's loads now; they retire during the MFMAs ----
        if (ci < 3) {
            const float* xcn = x + ((size_t)b * C_ + cbase + ci + 1) * PIX_;
#pragma unroll
            for (int k = 0; k < 4; k++) pv[k] = *(const float4*)&xcn[(t + k * 256) * 4];
        }

        f32x4 acc[4];
#pragma unroll
        for (int nt = 0; nt < 4; nt++) acc[nt] = (f32x4){0.f, 0.f, 0.f, 0.f};
#pragma unroll
        for (int ks = 0; ks < 2; ks++) {
            bf16x8 ah = pcA_h[ks], al_ = pcA_l[ks];
#pragma unroll
            for (int nt = 0; nt < 4; nt++) {
                bf16x8 bh = *(const bf16x8*)&Xh[(nt * 16 + col) * LDX + q * 8 + ks * 32];
                bf16x8 bl = *(const bf16x8*)&Xl[(nt * 16 + col) * LDX + q * 8 + ks * 32];
                acc[nt] = __builtin_amdgcn_mfma_f32_16x16x32_bf16(ah, bh, acc[nt], 0, 0, 0);
                acc[nt] = __builtin_amdgcn_mfma_f32_16x16x32_bf16(ah, bl, acc[nt], 0, 0, 0);
                acc[nt] = __builtin_amdgcn_mfma_f32_16x16x32_bf16(al_, bh, acc[nt], 0, 0, 0);
            }
        }
        // Z tile is wave-private (wave w writes rows i0..i0+15, reads the same);
        // compiler inserts the lgkm wait; no barrier needed (validated R0-R3).
#pragma unroll
        for (int nt = 0; nt < 4; nt++)
#pragma unroll
            for (int r = 0; r < 4; r++) {
                float v = acc[nt][r];
                u16 h = f2bf(v);
                int rw = i0 + q * 4 + r;
                Zh[rw * LDX + nt * 16 + col] = h;
                Zl[rw * LDX + nt * 16 + col] = f2bf(v - bf2f(h));
            }

        f32x4 acc2[4];
#pragma unroll
        for (int nt = 0; nt < 4; nt++) acc2[nt] = (f32x4){0.f, 0.f, 0.f, 0.f};
#pragma unroll
        for (int ks = 0; ks < 2; ks++) {
            bf16x8 ah = *(const bf16x8*)&Zh[(i0 + col) * LDX + q * 8 + ks * 32];
            bf16x8 al_ = *(const bf16x8*)&Zl[(i0 + col) * LDX + q * 8 + ks * 32];
#pragma unroll
            for (int nt = 0; nt < 4; nt++) {
                bf16x8 bh = *(const bf16x8*)&prh[(nt * 16 + col) * 64 + q * 8 + ks * 32];
                bf16x8 bl = *(const bf16x8*)&prl[(nt * 16 + col) * 64 + q * 8 + ks * 32];
                acc2[nt] = __builtin_amdgcn_mfma_f32_16x16x32_bf16(ah, bh, acc2[nt], 0, 0, 0);
                acc2[nt] = __builtin_amdgcn_mfma_f32_16x16x32_bf16(ah, bl, acc2[nt], 0, 0, 0);
                acc2[nt] = __builtin_amdgcn_mfma_f32_16x16x32_bf16(al_, bh, acc2[nt], 0, 0, 0);
            }
        }
        float* oc = out + ((size_t)b * C_ + cbase + ci) * PIX_;
#pragma unroll
        for (int nt = 0; nt < 4; nt++)
#pragma unroll
            for (int r = 0; r < 4; r++)
                oc[(i0 + q * 4 + r) * 64 + nt * 16 + col] = acc2[nt][r];
        __syncthreads();
    }
}

extern "C" void kernel_launch(void* const* d_in, const int* in_sizes, int n_in,
                              void* d_out, int out_size, void* d_ws, size_t ws_size,
                              hipStream_t stream) {
    const float* x = (const float*)d_in[0];
    const float* w1 = (const float*)d_in[1];
    const float* b1 = (const float*)d_in[2];
    const float* w2 = (const float*)d_in[3];
    const float* b2 = (const float*)d_in[4];
    const float* w_row = (const float*)d_in[5];
    const float* b_row = (const float*)d_in[6];
    const float* w_col = (const float*)d_in[7];
    const float* b_col = (const float*)d_in[8];
    float* out = (float*)d_out;

    char* ws = (char*)d_ws;
    u16* w1h = (u16*)(ws);                   //  65536 B
    u16* w1l = (u16*)(ws + 65536);           //  65536 B
    u16* w2h = (u16*)(ws + 131072);          //  131072 B
    u16* w2l = (u16*)(ws + 262144);          //  131072 B
    float* row_s = (float*)(ws + 393216);    //  8192 B
    float* col_s = (float*)(ws + 401408);    //  8192 B
    u16* prow_h = (u16*)(ws + 409600);       //  262144 B
    u16* prow_l = (u16*)(ws + 671744);       //  262144 B
    u16* pcol_h = (u16*)(ws + 933888);       //  262144 B
    u16* pcol_l = (u16*)(ws + 1196032);      //  262144 B

    hipLaunchKernelGGL(k_prep, dim3(384), dim3(256), 0, stream, w1, w2, w1h, w1l, w2h, w2l,
                       col_s, b_col);
    hipLaunchKernelGGL(k12_fused, dim3(64, 32), dim3(256), 0, stream,
                       x, w1h, w1l, b1, w2h, w2l, b2, w_row, b_row, w_col, row_s, col_s);
    hipLaunchKernelGGL(k4_diffsort, dim3(64), dim3(256), 0, stream,
                       row_s, col_s, prow_h, prow_l, pcol_h, pcol_l);
    hipLaunchKernelGGL(k5_permute, dim3(32, 32), dim3(256), 0, stream,
                       x, pcol_h, pcol_l, prow_h, prow_l, out);
}

// Round 6
// 269.694 us; speedup vs baseline: 1.3286x; 1.0230x over previous
//
#include <hip/hip_runtime.h>
#include <math.h>

#define B_    32
#define C_    128
#define N_    64
#define HID_  256
#define PIX_  4096
#define STEEP 50.0f
#define INV_PI 0.318309886183790671f
#define LDH   272  // LDS row pitch (u16): 32 h1 chunks (256) + 16 pad; x tile time-shares cols 128..255
#define LDX   72   // k5 pitch

typedef unsigned short u16;
typedef __attribute__((ext_vector_type(8))) short bf16x8;
typedef __attribute__((ext_vector_type(4))) float f32x4;

__device__ __forceinline__ u16 f2bf(float f) {
    unsigned int u = __builtin_bit_cast(unsigned int, f);
    unsigned int r = (u + 0x7FFFu + ((u >> 16) & 1u)) >> 16;
    return (u16)r;
}
__device__ __forceinline__ float bf2f(u16 h) {
    unsigned int u = ((unsigned int)h) << 16;
    return __builtin_bit_cast(float, u);
}
// swizzled LDS indices (chunk = 8 u16 = 16 B, rotated by row for bank spread)
__device__ __forceinline__ int h1_idx(int p, int k) {
    return p * LDH + (((k >> 3) + (p & 7)) & 31) * 8 + (k & 7);
}
__device__ __forceinline__ int x_idx(int p, int k) {
    return p * LDH + 128 + (((k >> 3) + (p & 7)) & 15) * 8 + (k & 7);
}

// ---------------- Kprep: decompose weights into bf16 hi/lo + init col_s ----------------
__global__ void k_prep(const float* __restrict__ w1, const float* __restrict__ w2,
                       u16* __restrict__ w1h, u16* __restrict__ w1l,
                       u16* __restrict__ w2h, u16* __restrict__ w2l,
                       float* __restrict__ col_s, const float* __restrict__ b_col) {
    int i = blockIdx.x * 256 + threadIdx.x;
    if (i < B_ * N_) col_s[i] = b_col[0];
    if (i < HID_ * C_) {
        float v = w1[i];
        u16 h = f2bf(v);
        w1h[i] = h;
        w1l[i] = f2bf(v - bf2f(h));
    } else {
        int j = i - HID_ * C_;
        if (j < HID_ * HID_) {
            float v = w2[j];
            u16 h = f2bf(v);
            w2h[j] = h;
            w2l[j] = f2bf(v - bf2f(h));
        }
    }
}

// ---------------- K12: fused conv1+conv2+scores, 64-px tile, 8 WAVES/block ----------------
// LDS 70144B caps at 2 blocks/CU regardless of block size; 512 threads doubles
// waves/CU (8->16, i.e. 2->4 per SIMD) at constant LDS. Per-wave: mf=2 (32 out ch).
__global__ __launch_bounds__(512) void k12_fused(
    const float* __restrict__ x,
    const u16* __restrict__ w1h, const u16* __restrict__ w1l,
    const float* __restrict__ b1,
    const u16* __restrict__ w2h, const u16* __restrict__ w2l,
    const float* __restrict__ b2, const float* __restrict__ w_row,
    const float* __restrict__ b_row, const float* __restrict__ w_col,
    float* __restrict__ row_s, float* __restrict__ col_s) {
    __shared__ __align__(16) u16 Lh[64 * LDH];   // 34816 B (h1 hi / x hi staging)
    __shared__ __align__(16) u16 Ll[64 * LDH];   // 34816 B (h1 lo / x lo staging)
    __shared__ float col_red[64];
    __shared__ float row_red;

    const int t = threadIdx.x;
    const int l = t & 63, w = t >> 6;            // w 0..7
    const int col = l & 15, q = l >> 4;
    const int hrow = blockIdx.x;
    const int b = blockIdx.y;
    const float* xb = x + (size_t)b * C_ * PIX_ + hrow * 64;

    if (t < 64) col_red[t] = 0.f;
    if (t == 0) row_red = 0.f;

    // ---- stage FULL x tile [64 p][128 c] -> swizzled cols 128..255 (one barrier) ----
    {
        const int pt = t & 15, ct = t >> 4;      // ct 0..31
#pragma unroll
        for (int cc = 0; cc < 2; cc++) {
            const int c = cc * 64 + 2 * ct;
            float4 v0 = *(const float4*)&xb[(size_t)c * PIX_ + pt * 4];
            float4 v1 = *(const float4*)&xb[(size_t)(c + 1) * PIX_ + pt * 4];
            float a0[4] = {v0.x, v0.y, v0.z, v0.w};
            float a1[4] = {v1.x, v1.y, v1.z, v1.w};
#pragma unroll
            for (int j = 0; j < 4; j++) {
                int p = pt * 4 + j;
                u16 h0 = f2bf(a0[j]), h1v = f2bf(a1[j]);
                u16 l0 = f2bf(a0[j] - bf2f(h0)), l1 = f2bf(a1[j] - bf2f(h1v));
                int idx = x_idx(p, c);
                *(unsigned int*)&Lh[idx] = (unsigned int)h0 | ((unsigned int)h1v << 16);
                *(unsigned int*)&Ll[idx] = (unsigned int)l0 | ((unsigned int)l1 << 16);
            }
        }
    }
    __syncthreads();

    // ---- conv1: 96 MFMAs/wave, pipelined A (global) + B (LDS) ----
    f32x4 acc[2][4];
#pragma unroll
    for (int i = 0; i < 2; i++)
#pragma unroll
        for (int j = 0; j < 4; j++) acc[i][j] = (f32x4){0.f, 0.f, 0.f, 0.f};

    bf16x8 ah[2], al_[2];
#pragma unroll
    for (int mf = 0; mf < 2; mf++) {
        size_t ro = (size_t)(32 * w + 16 * mf + col) * C_ + q * 8;
        ah[mf] = *(const bf16x8*)&w1h[ro];
        al_[mf] = *(const bf16x8*)&w1l[ro];
    }
#pragma unroll
    for (int kc = 0; kc < 4; kc++) {
        bf16x8 bh[4], bl[4];
#pragma unroll
        for (int nt = 0; nt < 4; nt++) {
            int idx = x_idx(nt * 16 + col, kc * 32 + q * 8);
            bh[nt] = *(const bf16x8*)&Lh[idx];
            bl[nt] = *(const bf16x8*)&Ll[idx];
        }
        bf16x8 ahn[2], aln[2];
        const int kn = (kc + 1) & 3;
#pragma unroll
        for (int mf = 0; mf < 2; mf++) {
            size_t ro = (size_t)(32 * w + 16 * mf + col) * C_ + kn * 32 + q * 8;
            ahn[mf] = *(const bf16x8*)&w1h[ro];
            aln[mf] = *(const bf16x8*)&w1l[ro];
        }
#pragma unroll
        for (int mf = 0; mf < 2; mf++)
#pragma unroll
            for (int nt = 0; nt < 4; nt++) {
                acc[mf][nt] = __builtin_amdgcn_mfma_f32_16x16x32_bf16(ah[mf], bh[nt], acc[mf][nt], 0, 0, 0);
                acc[mf][nt] = __builtin_amdgcn_mfma_f32_16x16x32_bf16(ah[mf], bl[nt], acc[mf][nt], 0, 0, 0);
                acc[mf][nt] = __builtin_amdgcn_mfma_f32_16x16x32_bf16(al_[mf], bh[nt], acc[mf][nt], 0, 0, 0);
            }
#pragma unroll
        for (int mf = 0; mf < 2; mf++) { ah[mf] = ahn[mf]; al_[mf] = aln[mf]; }
    }

    // prefetch conv2's first A-frags before the barrier
    bf16x8 ah2[2], al2[2];
#pragma unroll
    for (int mf = 0; mf < 2; mf++) {
        size_t ro = (size_t)(32 * w + 16 * mf + col) * HID_ + q * 8;
        ah2[mf] = *(const bf16x8*)&w2h[ro];
        al2[mf] = *(const bf16x8*)&w2l[ro];
    }
    __syncthreads();   // all x-frag reads done; rows can be overwritten with h1

    // ---- conv1 epilogue: relu(acc+b1) -> swizzled h1 hi/lo ----
#pragma unroll
    for (int mf = 0; mf < 2; mf++) {
        int o = 32 * w + 16 * mf + q * 4;
        float bias[4];
#pragma unroll
        for (int r = 0; r < 4; r++) bias[r] = b1[o + r];
#pragma unroll
        for (int nt = 0; nt < 4; nt++) {
            int p = nt * 16 + col;
            u16 hh[4], ll[4];
#pragma unroll
            for (int r = 0; r < 4; r++) {
                float v = fmaxf(acc[mf][nt][r] + bias[r], 0.f);
                u16 h = f2bf(v);
                hh[r] = h;
                ll[r] = f2bf(v - bf2f(h));
            }
            int idx = h1_idx(p, o);
            *(unsigned long long*)&Lh[idx] =
                (unsigned long long)hh[0] | ((unsigned long long)hh[1] << 16) |
                ((unsigned long long)hh[2] << 32) | ((unsigned long long)hh[3] << 48);
            *(unsigned long long*)&Ll[idx] =
                (unsigned long long)ll[0] | ((unsigned long long)ll[1] << 16) |
                ((unsigned long long)ll[2] << 32) | ((unsigned long long)ll[3] << 48);
        }
    }
    __syncthreads();

    // ---- conv2: 192 MFMAs/wave, pipelined ----
    f32x4 acc2[2][4];
#pragma unroll
    for (int i = 0; i < 2; i++)
#pragma unroll
        for (int j = 0; j < 4; j++) acc2[i][j] = (f32x4){0.f, 0.f, 0.f, 0.f};

#pragma unroll
    for (int kc = 0; kc < 8; kc++) {
        bf16x8 bh[4], bl[4];
#pragma unroll
        for (int nt = 0; nt < 4; nt++) {
            int idx = h1_idx(nt * 16 + col, kc * 32 + q * 8);
            bh[nt] = *(const bf16x8*)&Lh[idx];
            bl[nt] = *(const bf16x8*)&Ll[idx];
        }
        bf16x8 ahn[2], aln[2];
        const int kn = (kc + 1) & 7;
#pragma unroll
        for (int mf = 0; mf < 2; mf++) {
            size_t ro = (size_t)(32 * w + 16 * mf + col) * HID_ + kn * 32 + q * 8;
            ahn[mf] = *(const bf16x8*)&w2h[ro];
            aln[mf] = *(const bf16x8*)&w2l[ro];
        }
#pragma unroll
        for (int mf = 0; mf < 2; mf++)
#pragma unroll
            for (int nt = 0; nt < 4; nt++) {
                acc2[mf][nt] = __builtin_amdgcn_mfma_f32_16x16x32_bf16(ah2[mf], bh[nt], acc2[mf][nt], 0, 0, 0);
                acc2[mf][nt] = __builtin_amdgcn_mfma_f32_16x16x32_bf16(ah2[mf], bl[nt], acc2[mf][nt], 0, 0, 0);
                acc2[mf][nt] = __builtin_amdgcn_mfma_f32_16x16x32_bf16(al2[mf], bh[nt], acc2[mf][nt], 0, 0, 0);
            }
#pragma unroll
        for (int mf = 0; mf < 2; mf++) { ah2[mf] = ahn[mf]; al2[mf] = aln[mf]; }
    }

    // ---- score epilogue ----
    float rpart = 0.f;
    float cpart[4] = {0.f, 0.f, 0.f, 0.f};
#pragma unroll
    for (int mf = 0; mf < 2; mf++) {
        int o = 32 * w + 16 * mf + q * 4;
#pragma unroll
        for (int r = 0; r < 4; r++) {
            float bias = b2[o + r];
            float wcv = w_col[(o + r) * N_ + hrow];
#pragma unroll
            for (int nt = 0; nt < 4; nt++) {
                int wc = nt * 16 + col;
                float v = fmaxf(acc2[mf][nt][r] + bias, 0.f);
                rpart += v * w_row[(o + r) * N_ + wc];
                cpart[nt] += v * wcv;
            }
        }
    }
#pragma unroll
    for (int off = 32; off; off >>= 1) rpart += __shfl_xor(rpart, off, 64);
    if (l == 0) atomicAdd(&row_red, rpart);
#pragma unroll
    for (int nt = 0; nt < 4; nt++) {
        float cp = cpart[nt];
        cp += __shfl_xor(cp, 16, 64);
        cp += __shfl_xor(cp, 32, 64);
        if (l < 16) atomicAdd(&col_red[nt * 16 + l], cp);
    }
    __syncthreads();
    if (t < 64) atomicAdd(&col_s[b * N_ + t], col_red[t]);
    if (t == 0) row_s[b * N_ + hrow] = b_row[0] + row_red;
}

// ---------------- K4: diff bitonic sort, register-resident P, shuffle-only ----------------
__global__ __launch_bounds__(256) void k4_diffsort(const float* __restrict__ row_s,
                                                   const float* __restrict__ col_s,
                                                   u16* __restrict__ prow_h, u16* __restrict__ prow_l,
                                                   u16* __restrict__ pcol_h, u16* __restrict__ pcol_l) {
    const int t = threadIdx.x;
    const int lane = t & 63, w = t >> 6;
    const int which = blockIdx.x & 1;
    const int b = blockIdx.x >> 1;
    const float* sc = which ? col_s : row_s;
    u16* Ph = which ? pcol_h : prow_h;
    u16* Pl = which ? pcol_l : prow_l;

    float xv = sc[b * 64 + lane];
    float P[16];
#pragma unroll
    for (int r = 0; r < 16; r++) P[r] = ((w * 16 + r) == lane) ? 1.f : 0.f;

#pragma unroll
    for (int bl = 0; bl < 6; bl++) {
#pragma unroll
        for (int ly = 0; ly <= bl; ly++) {
            const int sh = bl - ly;
            const int m = 1 << sh;
            float xp = __shfl_xor(xv, m, 64);
            int lower = ((lane >> sh) & 1) ^ 1;            // lane is the low member of its pair
            int swp = (lane >> (bl + 1)) & 1;              // direction flip for this pair
            float diff = (lower ^ swp) ? (xp - xv) : (xv - xp);   // xb - xa (same value both lanes)
            float al = atanf(diff * STEEP) * INV_PI + 0.5f;
            xv = al * xv + (1.f - al) * xp;
#pragma unroll
            for (int r = 0; r < 16; r++) {
                float Pp = __shfl_xor(P[r], m, 64);
                P[r] = al * P[r] + (1.f - al) * Pp;
            }
        }
    }
#pragma unroll
    for (int r = 0; r < 16; r++) {
        float v = P[r];
        u16 h = f2bf(v);
        int row = w * 16 + r;
        Ph[(size_t)b * 4096 + row * 64 + lane] = h;
        Pl[(size_t)b * 4096 + row * 64 + lane] = f2bf(v - bf2f(h));
    }
}

// ---------------- K5: double permutation, SWAPPED-operand MFMAs ----------------
// mfma(B,A) = (A*B)^T with identical operand reads; the transposed D makes r the
// fastest output index, so Z writes pack to 8x ds_write_b64 (was 32x b16) and
// out stores pack to 4x dwordx4 (was 16x dword). P_row frags hoisted to regs.
__global__ __launch_bounds__(256) void k5_permute(const float* __restrict__ x,
                                                  const u16* __restrict__ pcol_h,
                                                  const u16* __restrict__ pcol_l,
                                                  const u16* __restrict__ prow_h,
                                                  const u16* __restrict__ prow_l,
                                                  float* __restrict__ out) {
    __shared__ __align__(16) u16 Xh[64 * LDX];
    __shared__ __align__(16) u16 Xl[64 * LDX];
    __shared__ __align__(16) u16 Zh[64 * LDX];
    __shared__ __align__(16) u16 Zl[64 * LDX];
    const int t = threadIdx.x;
    const int l = t & 63, w = t >> 6;
    const int col = l & 15, q = l >> 4;
    const int b = blockIdx.y;
    const int cbase = blockIdx.x * 4;
    const int i0 = w * 16;

    const u16* pch = pcol_h + (size_t)b * 4096;
    const u16* pcl = pcol_l + (size_t)b * 4096;
    const u16* prh = prow_h + (size_t)b * 4096;
    const u16* prl = prow_l + (size_t)b * 4096;

    // hoisted P_col frags (as 2nd mfma operand) and P_row frags (as 1st operand)
    bf16x8 pcA_h[2], pcA_l[2];
#pragma unroll
    for (int ks = 0; ks < 2; ks++) {
        pcA_h[ks] = *(const bf16x8*)&pch[(i0 + col) * 64 + q * 8 + ks * 32];
        pcA_l[ks] = *(const bf16x8*)&pcl[(i0 + col) * 64 + q * 8 + ks * 32];
    }
    bf16x8 prA_h[2][4], prA_l[2][4];
#pragma unroll
    for (int ks = 0; ks < 2; ks++)
#pragma unroll
        for (int ntj = 0; ntj < 4; ntj++) {
            prA_h[ks][ntj] = *(const bf16x8*)&prh[(ntj * 16 + col) * 64 + q * 8 + ks * 32];
            prA_l[ks][ntj] = *(const bf16x8*)&prl[(ntj * 16 + col) * 64 + q * 8 + ks * 32];
        }

    for (int ci = 0; ci < 4; ci++) {
        const int c = cbase + ci;
        const float* xc = x + ((size_t)b * C_ + c) * PIX_;
#pragma unroll
        for (int k = 0; k < 4; k++) {
            int f = t + k * 256;
            int rw = f >> 4, c4 = f & 15;
            float4 v = *(const float4*)&xc[f * 4];
            u16 h0 = f2bf(v.x), h1 = f2bf(v.y), h2 = f2bf(v.z), h3 = f2bf(v.w);
            ushort4 hv = {h0, h1, h2, h3};
            ushort4 lv = {f2bf(v.x - bf2f(h0)), f2bf(v.y - bf2f(h1)),
                          f2bf(v.z - bf2f(h2)), f2bf(v.w - bf2f(h3))};
            *(ushort4*)&Xh[rw * LDX + c4 * 4] = hv;
            *(ushort4*)&Xl[rw * LDX + c4 * 4] = lv;
        }
        __syncthreads();

        // ---- GEMM1 (swapped): acc[ntx][r] = Z[i0+col][ntx*16+q*4+r] ----
        f32x4 acc[4];
#pragma unroll
        for (int nt = 0; nt < 4; nt++) acc[nt] = (f32x4){0.f, 0.f, 0.f, 0.f};
#pragma unroll
        for (int ks = 0; ks < 2; ks++) {
            bf16x8 ph = pcA_h[ks], pl = pcA_l[ks];
#pragma unroll
            for (int nt = 0; nt < 4; nt++) {
                bf16x8 xh8 = *(const bf16x8*)&Xh[(nt * 16 + col) * LDX + q * 8 + ks * 32];
                bf16x8 xl8 = *(const bf16x8*)&Xl[(nt * 16 + col) * LDX + q * 8 + ks * 32];
                acc[nt] = __builtin_amdgcn_mfma_f32_16x16x32_bf16(xh8, ph, acc[nt], 0, 0, 0);
                acc[nt] = __builtin_amdgcn_mfma_f32_16x16x32_bf16(xl8, ph, acc[nt], 0, 0, 0);
                acc[nt] = __builtin_amdgcn_mfma_f32_16x16x32_bf16(xh8, pl, acc[nt], 0, 0, 0);
            }
        }
        // ---- packed Z write: row (i0+col), 4 consecutive k -> ds_write_b64 ----
        // Z rows i0..i0+15 are wave-private (same-wave write->read; compiler
        // inserts the lgkm wait; validated R0-R4 with the scalar variant).
#pragma unroll
        for (int nt = 0; nt < 4; nt++) {
            u16 hh[4], ll[4];
#pragma unroll
            for (int r = 0; r < 4; r++) {
                float v = acc[nt][r];
                u16 h = f2bf(v);
                hh[r] = h;
                ll[r] = f2bf(v - bf2f(h));
            }
            int zi = (i0 + col) * LDX + nt * 16 + q * 4;
            *(unsigned long long*)&Zh[zi] =
                (unsigned long long)hh[0] | ((unsigned long long)hh[1] << 16) |
                ((unsigned long long)hh[2] << 32) | ((unsigned long long)hh[3] << 48);
            *(unsigned long long*)&Zl[zi] =
                (unsigned long long)ll[0] | ((unsigned long long)ll[1] << 16) |
                ((unsigned long long)ll[2] << 32) | ((unsigned long long)ll[3] << 48);
        }

        // ---- GEMM2 (swapped): acc2[ntj][r] = out[i0+col][ntj*16+q*4+r] ----
        f32x4 acc2[4];
#pragma unroll
        for (int nt = 0; nt < 4; nt++) acc2[nt] = (f32x4){0.f, 0.f, 0.f, 0.f};
#pragma unroll
        for (int ks = 0; ks < 2; ks++) {
            bf16x8 zh8 = *(const bf16x8*)&Zh[(i0 + col) * LDX + q * 8 + ks * 32];
            bf16x8 zl8 = *(const bf16x8*)&Zl[(i0 + col) * LDX + q * 8 + ks * 32];
#pragma unroll
            for (int ntj = 0; ntj < 4; ntj++) {
                acc2[ntj] = __builtin_amdgcn_mfma_f32_16x16x32_bf16(prA_h[ks][ntj], zh8, acc2[ntj], 0, 0, 0);
                acc2[ntj] = __builtin_amdgcn_mfma_f32_16x16x32_bf16(prA_l[ks][ntj], zh8, acc2[ntj], 0, 0, 0);
                acc2[ntj] = __builtin_amdgcn_mfma_f32_16x16x32_bf16(prA_h[ks][ntj], zl8, acc2[ntj], 0, 0, 0);
            }
        }
        // ---- packed out store: float4 per (ntj) ----
        float* oc = out + ((size_t)b * C_ + c) * PIX_;
#pragma unroll
        for (int ntj = 0; ntj < 4; ntj++) {
            float4 vv = {acc2[ntj][0], acc2[ntj][1], acc2[ntj][2], acc2[ntj][3]};
            *(float4*)&oc[(i0 + col) * 64 + ntj * 16 + q * 4] = vv;
        }
        __syncthreads();
    }
}

extern "C" void kernel_launch(void* const* d_in, const int* in_sizes, int n_in,
                              void* d_out, int out_size, void* d_ws, size_t ws_size,
                              hipStream_t stream) {
    const float* x = (const float*)d_in[0];
    const float* w1 = (const float*)d_in[1];
    const float* b1 = (const float*)d_in[2];
    const float* w2 = (const float*)d_in[3];
    const float* b2 = (const float*)d_in[4];
    const float* w_row = (const float*)d_in[5];
    const float* b_row = (const float*)d_in[6];
    const float* w_col = (const float*)d_in[7];
    const float* b_col = (const float*)d_in[8];
    float* out = (float*)d_out;

    char* ws = (char*)d_ws;
    u16* w1h = (u16*)(ws);                   //  65536 B
    u16* w1l = (u16*)(ws + 65536);           //  65536 B
    u16* w2h = (u16*)(ws + 131072);          //  131072 B
    u16* w2l = (u16*)(ws + 262144);          //  131072 B
    float* row_s = (float*)(ws + 393216);    //  8192 B
    float* col_s = (float*)(ws + 401408);    //  8192 B
    u16* prow_h = (u16*)(ws + 409600);       //  262144 B
    u16* prow_l = (u16*)(ws + 671744);       //  262144 B
    u16* pcol_h = (u16*)(ws + 933888);       //  262144 B
    u16* pcol_l = (u16*)(ws + 1196032);      //  262144 B

    hipLaunchKernelGGL(k_prep, dim3(384), dim3(256), 0, stream, w1, w2, w1h, w1l, w2h, w2l,
                       col_s, b_col);
    hipLaunchKernelGGL(k12_fused, dim3(64, 32), dim3(512), 0, stream,
                       x, w1h, w1l, b1, w2h, w2l, b2, w_row, b_row, w_col, row_s, col_s);
    hipLaunchKernelGGL(k4_diffsort, dim3(64), dim3(256), 0, stream,
                       row_s, col_s, prow_h, prow_l, pcol_h, pcol_l);
    hipLaunchKernelGGL(k5_permute, dim3(32, 32), dim3(256), 0, stream,
                       x, pcol_h, pcol_l, prow_h, prow_l, out);
}

// Round 7
// 257.126 us; speedup vs baseline: 1.3936x; 1.0489x over previous
//
#include <hip/hip_runtime.h>
#include <math.h>

#define B_    32
#define C_    128
#define N_    64
#define HID_  256
#define PIX_  4096
#define STEEP 50.0f
#define INV_PI 0.318309886183790671f
#define LDH   272  // LDS row pitch (u16): 32 h1 chunks (256) + 16 pad; x tile time-shares cols 128..255
#define LDX   72   // k5 pitch

#if defined(__has_builtin)
#if __has_builtin(__builtin_amdgcn_mfma_f32_16x16x16bf16_1k)
#define HAVE_MFMA16 1
#endif
#endif
#ifndef HAVE_MFMA16
#define HAVE_MFMA16 0
#endif

typedef unsigned short u16;
typedef __attribute__((ext_vector_type(8))) short bf16x8;
typedef __attribute__((ext_vector_type(4))) short bf16x4;
typedef __attribute__((ext_vector_type(4))) float f32x4;

__device__ __forceinline__ u16 f2bf(float f) {
    unsigned int u = __builtin_bit_cast(unsigned int, f);
    unsigned int r = (u + 0x7FFFu + ((u >> 16) & 1u)) >> 16;
    return (u16)r;
}
__device__ __forceinline__ float bf2f(u16 h) {
    unsigned int u = ((unsigned int)h) << 16;
    return __builtin_bit_cast(float, u);
}
// swizzled LDS indices (chunk = 8 u16 = 16 B, rotated by row for bank spread)
__device__ __forceinline__ int h1_idx(int p, int k) {
    return p * LDH + (((k >> 3) + (p & 7)) & 31) * 8 + (k & 7);
}
// R7: rotation (p>>2)&7 — staging writes have p-stride 4, (p&7) collapsed to 2
// rotations (8-way write conflict, 11M counted); (p>>2)&7 gives 8 rotations
// (2-way = free). conv1 reads stay <=2-way. Same bijection -> correctness-safe.
__device__ __forceinline__ int x_idx(int p, int k) {
    return p * LDH + 128 + (((k >> 3) + ((p >> 2) & 7)) & 15) * 8 + (k & 7);
}

// ---------------- Kprep: decompose weights into bf16 hi/lo + init col_s ----------------
__global__ void k_prep(const float* __restrict__ w1, const float* __restrict__ w2,
                       u16* __restrict__ w1h, u16* __restrict__ w1l,
                       u16* __restrict__ w2h, u16* __restrict__ w2l,
                       float* __restrict__ col_s, const float* __restrict__ b_col) {
    int i = blockIdx.x * 256 + threadIdx.x;
    if (i < B_ * N_) col_s[i] = b_col[0];
    if (i < HID_ * C_) {
        float v = w1[i];
        u16 h = f2bf(v);
        w1h[i] = h;
        w1l[i] = f2bf(v - bf2f(h));
    } else {
        int j = i - HID_ * C_;
        if (j < HID_ * HID_) {
            float v = w2[j];
            u16 h = f2bf(v);
            w2h[j] = h;
            w2l[j] = f2bf(v - bf2f(h));
        }
    }
}

// ---------------- K12: fused conv1+conv2+scores, 64-px tile, 8 waves/block ----------------
__global__ __launch_bounds__(512) void k12_fused(
    const float* __restrict__ x,
    const u16* __restrict__ w1h, const u16* __restrict__ w1l,
    const float* __restrict__ b1,
    const u16* __restrict__ w2h, const u16* __restrict__ w2l,
    const float* __restrict__ b2, const float* __restrict__ w_row,
    const float* __restrict__ b_row, const float* __restrict__ w_col,
    float* __restrict__ row_s, float* __restrict__ col_s) {
    __shared__ __align__(16) u16 Lh[64 * LDH];   // 34816 B (h1 hi / x hi staging)
    __shared__ __align__(16) u16 Ll[64 * LDH];   // 34816 B (h1 lo / x lo staging)
    __shared__ float col_red[64];
    __shared__ float row_red;

    const int t = threadIdx.x;
    const int l = t & 63, w = t >> 6;            // w 0..7
    const int col = l & 15, q = l >> 4;
    const int hrow = blockIdx.x;
    const int b = blockIdx.y;
    const float* xb = x + (size_t)b * C_ * PIX_ + hrow * 64;

    if (t < 64) col_red[t] = 0.f;
    if (t == 0) row_red = 0.f;

    // ---- stage FULL x tile [64 p][128 c] -> swizzled cols 128..255 (one barrier) ----
    {
        const int pt = t & 15, ct = t >> 4;      // ct 0..31
#pragma unroll
        for (int cc = 0; cc < 2; cc++) {
            const int c = cc * 64 + 2 * ct;
            float4 v0 = *(const float4*)&xb[(size_t)c * PIX_ + pt * 4];
            float4 v1 = *(const float4*)&xb[(size_t)(c + 1) * PIX_ + pt * 4];
            float a0[4] = {v0.x, v0.y, v0.z, v0.w};
            float a1[4] = {v1.x, v1.y, v1.z, v1.w};
#pragma unroll
            for (int j = 0; j < 4; j++) {
                int p = pt * 4 + j;
                u16 h0 = f2bf(a0[j]), h1v = f2bf(a1[j]);
                u16 l0 = f2bf(a0[j] - bf2f(h0)), l1 = f2bf(a1[j] - bf2f(h1v));
                int idx = x_idx(p, c);
                *(unsigned int*)&Lh[idx] = (unsigned int)h0 | ((unsigned int)h1v << 16);
                *(unsigned int*)&Ll[idx] = (unsigned int)l0 | ((unsigned int)l1 << 16);
            }
        }
    }
    __syncthreads();

    // ---- conv1: 96 MFMAs/wave, pipelined A (global) + B (LDS) ----
    f32x4 acc[2][4];
#pragma unroll
    for (int i = 0; i < 2; i++)
#pragma unroll
        for (int j = 0; j < 4; j++) acc[i][j] = (f32x4){0.f, 0.f, 0.f, 0.f};

    bf16x8 ah[2], al_[2];
#pragma unroll
    for (int mf = 0; mf < 2; mf++) {
        size_t ro = (size_t)(32 * w + 16 * mf + col) * C_ + q * 8;
        ah[mf] = *(const bf16x8*)&w1h[ro];
        al_[mf] = *(const bf16x8*)&w1l[ro];
    }
#pragma unroll
    for (int kc = 0; kc < 4; kc++) {
        bf16x8 bh[4], bl[4];
#pragma unroll
        for (int nt = 0; nt < 4; nt++) {
            int idx = x_idx(nt * 16 + col, kc * 32 + q * 8);
            bh[nt] = *(const bf16x8*)&Lh[idx];
            bl[nt] = *(const bf16x8*)&Ll[idx];
        }
        bf16x8 ahn[2], aln[2];
        const int kn = (kc + 1) & 3;
#pragma unroll
        for (int mf = 0; mf < 2; mf++) {
            size_t ro = (size_t)(32 * w + 16 * mf + col) * C_ + kn * 32 + q * 8;
            ahn[mf] = *(const bf16x8*)&w1h[ro];
            aln[mf] = *(const bf16x8*)&w1l[ro];
        }
#pragma unroll
        for (int mf = 0; mf < 2; mf++)
#pragma unroll
            for (int nt = 0; nt < 4; nt++) {
                acc[mf][nt] = __builtin_amdgcn_mfma_f32_16x16x32_bf16(ah[mf], bh[nt], acc[mf][nt], 0, 0, 0);
                acc[mf][nt] = __builtin_amdgcn_mfma_f32_16x16x32_bf16(ah[mf], bl[nt], acc[mf][nt], 0, 0, 0);
                acc[mf][nt] = __builtin_amdgcn_mfma_f32_16x16x32_bf16(al_[mf], bh[nt], acc[mf][nt], 0, 0, 0);
            }
#pragma unroll
        for (int mf = 0; mf < 2; mf++) { ah[mf] = ahn[mf]; al_[mf] = aln[mf]; }
    }

    // prefetch conv2's first A-frags before the barrier
    bf16x8 ah2[2], al2[2];
#pragma unroll
    for (int mf = 0; mf < 2; mf++) {
        size_t ro = (size_t)(32 * w + 16 * mf + col) * HID_ + q * 8;
        ah2[mf] = *(const bf16x8*)&w2h[ro];
        al2[mf] = *(const bf16x8*)&w2l[ro];
    }
    __syncthreads();   // all x-frag reads done; rows can be overwritten with h1

    // ---- conv1 epilogue: relu(acc+b1) -> swizzled h1 hi/lo ----
#pragma unroll
    for (int mf = 0; mf < 2; mf++) {
        int o = 32 * w + 16 * mf + q * 4;
        float bias[4];
#pragma unroll
        for (int r = 0; r < 4; r++) bias[r] = b1[o + r];
#pragma unroll
        for (int nt = 0; nt < 4; nt++) {
            int p = nt * 16 + col;
            u16 hh[4], ll[4];
#pragma unroll
            for (int r = 0; r < 4; r++) {
                float v = fmaxf(acc[mf][nt][r] + bias[r], 0.f);
                u16 h = f2bf(v);
                hh[r] = h;
                ll[r] = f2bf(v - bf2f(h));
            }
            int idx = h1_idx(p, o);
            *(unsigned long long*)&Lh[idx] =
                (unsigned long long)hh[0] | ((unsigned long long)hh[1] << 16) |
                ((unsigned long long)hh[2] << 32) | ((unsigned long long)hh[3] << 48);
            *(unsigned long long*)&Ll[idx] =
                (unsigned long long)ll[0] | ((unsigned long long)ll[1] << 16) |
                ((unsigned long long)ll[2] << 32) | ((unsigned long long)ll[3] << 48);
        }
    }
    __syncthreads();

    // ---- conv2: 192 MFMAs/wave, pipelined ----
    f32x4 acc2[2][4];
#pragma unroll
    for (int i = 0; i < 2; i++)
#pragma unroll
        for (int j = 0; j < 4; j++) acc2[i][j] = (f32x4){0.f, 0.f, 0.f, 0.f};

#pragma unroll
    for (int kc = 0; kc < 8; kc++) {
        bf16x8 bh[4], bl[4];
#pragma unroll
        for (int nt = 0; nt < 4; nt++) {
            int idx = h1_idx(nt * 16 + col, kc * 32 + q * 8);
            bh[nt] = *(const bf16x8*)&Lh[idx];
            bl[nt] = *(const bf16x8*)&Ll[idx];
        }
        bf16x8 ahn[2], aln[2];
        const int kn = (kc + 1) & 7;
#pragma unroll
        for (int mf = 0; mf < 2; mf++) {
            size_t ro = (size_t)(32 * w + 16 * mf + col) * HID_ + kn * 32 + q * 8;
            ahn[mf] = *(const bf16x8*)&w2h[ro];
            aln[mf] = *(const bf16x8*)&w2l[ro];
        }
#pragma unroll
        for (int mf = 0; mf < 2; mf++)
#pragma unroll
            for (int nt = 0; nt < 4; nt++) {
                acc2[mf][nt] = __builtin_amdgcn_mfma_f32_16x16x32_bf16(ah2[mf], bh[nt], acc2[mf][nt], 0, 0, 0);
                acc2[mf][nt] = __builtin_amdgcn_mfma_f32_16x16x32_bf16(ah2[mf], bl[nt], acc2[mf][nt], 0, 0, 0);
                acc2[mf][nt] = __builtin_amdgcn_mfma_f32_16x16x32_bf16(al2[mf], bh[nt], acc2[mf][nt], 0, 0, 0);
            }
#pragma unroll
        for (int mf = 0; mf < 2; mf++) { ah2[mf] = ahn[mf]; al2[mf] = aln[mf]; }
    }

    // ---- score epilogue ----
    float rpart = 0.f;
    float cpart[4] = {0.f, 0.f, 0.f, 0.f};
#pragma unroll
    for (int mf = 0; mf < 2; mf++) {
        int o = 32 * w + 16 * mf + q * 4;
#pragma unroll
        for (int r = 0; r < 4; r++) {
            float bias = b2[o + r];
            float wcv = w_col[(o + r) * N_ + hrow];
#pragma unroll
            for (int nt = 0; nt < 4; nt++) {
                int wc = nt * 16 + col;
                float v = fmaxf(acc2[mf][nt][r] + bias, 0.f);
                rpart += v * w_row[(o + r) * N_ + wc];
                cpart[nt] += v * wcv;
            }
        }
    }
#pragma unroll
    for (int off = 32; off; off >>= 1) rpart += __shfl_xor(rpart, off, 64);
    if (l == 0) atomicAdd(&row_red, rpart);
#pragma unroll
    for (int nt = 0; nt < 4; nt++) {
        float cp = cpart[nt];
        cp += __shfl_xor(cp, 16, 64);
        cp += __shfl_xor(cp, 32, 64);
        if (l < 16) atomicAdd(&col_red[nt * 16 + l], cp);
    }
    __syncthreads();
    if (t < 64) atomicAdd(&col_s[b * N_ + t], col_red[t]);
    if (t == 0) row_s[b * N_ + hrow] = b_row[0] + row_red;
}

// ---------------- K4: diff bitonic sort, register-resident P, shuffle-only ----------------
__global__ __launch_bounds__(256) void k4_diffsort(const float* __restrict__ row_s,
                                                   const float* __restrict__ col_s,
                                                   u16* __restrict__ prow_h, u16* __restrict__ prow_l,
                                                   u16* __restrict__ pcol_h, u16* __restrict__ pcol_l) {
    const int t = threadIdx.x;
    const int lane = t & 63, w = t >> 6;
    const int which = blockIdx.x & 1;
    const int b = blockIdx.x >> 1;
    const float* sc = which ? col_s : row_s;
    u16* Ph = which ? pcol_h : prow_h;
    u16* Pl = which ? pcol_l : prow_l;

    float xv = sc[b * 64 + lane];
    float P[16];
#pragma unroll
    for (int r = 0; r < 16; r++) P[r] = ((w * 16 + r) == lane) ? 1.f : 0.f;

#pragma unroll
    for (int bl = 0; bl < 6; bl++) {
#pragma unroll
        for (int ly = 0; ly <= bl; ly++) {
            const int sh = bl - ly;
            const int m = 1 << sh;
            float xp = __shfl_xor(xv, m, 64);
            int lower = ((lane >> sh) & 1) ^ 1;
            int swp = (lane >> (bl + 1)) & 1;
            float diff = (lower ^ swp) ? (xp - xv) : (xv - xp);
            float al = atanf(diff * STEEP) * INV_PI + 0.5f;
            xv = al * xv + (1.f - al) * xp;
#pragma unroll
            for (int r = 0; r < 16; r++) {
                float Pp = __shfl_xor(P[r], m, 64);
                P[r] = al * P[r] + (1.f - al) * Pp;
            }
        }
    }
#pragma unroll
    for (int r = 0; r < 16; r++) {
        float v = P[r];
        u16 h = f2bf(v);
        int row = w * 16 + r;
        Ph[(size_t)b * 4096 + row * 64 + lane] = h;
        Pl[(size_t)b * 4096 + row * 64 + lane] = f2bf(v - bf2f(h));
    }
}

// ---------------- K5: double permutation; GEMM2 register-chained via 16x16x16 ----------------
// GEMM1 (swapped) leaves lane (col,q) holding Z[i0+col][kc*16+q*4+r] — exactly the
// B-fragment layout of mfma_f32_16x16x16_bf16 (k=(l>>4)*4+j). GEMM2 thus consumes
// Z directly from registers: no Z LDS round-trip, no lgkm chain. Freed LDS funds a
// double-buffered X (1 barrier/channel, stage overlaps compute).
__global__ __launch_bounds__(256) void k5_permute(const float* __restrict__ x,
                                                  const u16* __restrict__ pcol_h,
                                                  const u16* __restrict__ pcol_l,
                                                  const u16* __restrict__ prow_h,
                                                  const u16* __restrict__ prow_l,
                                                  float* __restrict__ out) {
    __shared__ __align__(16) u16 Xh[2][64 * LDX];
    __shared__ __align__(16) u16 Xl[2][64 * LDX];
#if !HAVE_MFMA16
    __shared__ __align__(16) u16 Zh[64 * LDX];
    __shared__ __align__(16) u16 Zl[64 * LDX];
#endif
    const int t = threadIdx.x;
    const int l = t & 63, w = t >> 6;
    const int col = l & 15, q = l >> 4;
    const int b = blockIdx.y;
    const int cbase = blockIdx.x * 4;
    const int i0 = w * 16;

    const u16* pch = pcol_h + (size_t)b * 4096;
    const u16* pcl = pcol_l + (size_t)b * 4096;
    const u16* prh = prow_h + (size_t)b * 4096;
    const u16* prl = prow_l + (size_t)b * 4096;

    // P_col fragments (GEMM1 B-operand)
    bf16x8 pcA_h[2], pcA_l[2];
#pragma unroll
    for (int ks = 0; ks < 2; ks++) {
        pcA_h[ks] = *(const bf16x8*)&pch[(i0 + col) * 64 + q * 8 + ks * 32];
        pcA_l[ks] = *(const bf16x8*)&pcl[(i0 + col) * 64 + q * 8 + ks * 32];
    }
#if HAVE_MFMA16
    // P_row fragments for 16x16x16 GEMM2: A[m=col][k=q*4+j], K-chunk kc, out-block ntj
    bf16x4 prH[4][4], prL[4][4];
#pragma unroll
    for (int kc = 0; kc < 4; kc++)
#pragma unroll
        for (int ntj = 0; ntj < 4; ntj++) {
            prH[kc][ntj] = *(const bf16x4*)&prh[(ntj * 16 + col) * 64 + kc * 16 + q * 4];
            prL[kc][ntj] = *(const bf16x4*)&prl[(ntj * 16 + col) * 64 + kc * 16 + q * 4];
        }
#else
    bf16x8 prA_h[2][4], prA_l[2][4];
#pragma unroll
    for (int ks = 0; ks < 2; ks++)
#pragma unroll
        for (int ntj = 0; ntj < 4; ntj++) {
            prA_h[ks][ntj] = *(const bf16x8*)&prh[(ntj * 16 + col) * 64 + q * 8 + ks * 32];
            prA_l[ks][ntj] = *(const bf16x8*)&prl[(ntj * 16 + col) * 64 + q * 8 + ks * 32];
        }
#endif

    // ---- stage channel 0 into buffer 0 ----
    {
        const float* xc = x + ((size_t)b * C_ + cbase) * PIX_;
#pragma unroll
        for (int k = 0; k < 4; k++) {
            int f = t + k * 256;
            int rw = f >> 4, c4 = f & 15;
            float4 v = *(const float4*)&xc[f * 4];
            u16 h0 = f2bf(v.x), h1 = f2bf(v.y), h2 = f2bf(v.z), h3 = f2bf(v.w);
            ushort4 hv = {h0, h1, h2, h3};
            ushort4 lv = {f2bf(v.x - bf2f(h0)), f2bf(v.y - bf2f(h1)),
                          f2bf(v.z - bf2f(h2)), f2bf(v.w - bf2f(h3))};
            *(ushort4*)&Xh[0][rw * LDX + c4 * 4] = hv;
            *(ushort4*)&Xl[0][rw * LDX + c4 * 4] = lv;
        }
    }

    for (int ci = 0; ci < 4; ci++) {
        const int cur = ci & 1;
        __syncthreads();   // buf[cur] fully staged; prev iter's reads of buf[cur] done

        // issue next channel's loads early (retire under this channel's compute)
        float4 pv[4];
        if (ci < 3) {
            const float* xcn = x + ((size_t)b * C_ + cbase + ci + 1) * PIX_;
#pragma unroll
            for (int k = 0; k < 4; k++) pv[k] = *(const float4*)&xcn[(t + k * 256) * 4];
        }

        // ---- GEMM1 (swapped): acc[nt][r] = Z[i0+col][nt*16+q*4+r] ----
        f32x4 acc[4];
#pragma unroll
        for (int nt = 0; nt < 4; nt++) acc[nt] = (f32x4){0.f, 0.f, 0.f, 0.f};
#pragma unroll
        for (int ks = 0; ks < 2; ks++) {
            bf16x8 ph = pcA_h[ks], pl = pcA_l[ks];
#pragma unroll
            for (int nt = 0; nt < 4; nt++) {
                bf16x8 xh8 = *(const bf16x8*)&Xh[cur][(nt * 16 + col) * LDX + q * 8 + ks * 32];
                bf16x8 xl8 = *(const bf16x8*)&Xl[cur][(nt * 16 + col) * LDX + q * 8 + ks * 32];
                acc[nt] = __builtin_amdgcn_mfma_f32_16x16x32_bf16(xh8, ph, acc[nt], 0, 0, 0);
                acc[nt] = __builtin_amdgcn_mfma_f32_16x16x32_bf16(xl8, ph, acc[nt], 0, 0, 0);
                acc[nt] = __builtin_amdgcn_mfma_f32_16x16x32_bf16(xh8, pl, acc[nt], 0, 0, 0);
            }
        }

        f32x4 acc2[4];
#pragma unroll
        for (int nt = 0; nt < 4; nt++) acc2[nt] = (f32x4){0.f, 0.f, 0.f, 0.f};
#if HAVE_MFMA16
        // ---- Z -> bf16 hi/lo in registers (16x16x16 B-fragments) ----
        bf16x4 zH[4], zL[4];
#pragma unroll
        for (int kc = 0; kc < 4; kc++) {
#pragma unroll
            for (int j = 0; j < 4; j++) {
                float v = acc[kc][j];
                u16 h = f2bf(v);
                zH[kc][j] = (short)h;
                zL[kc][j] = (short)f2bf(v - bf2f(h));
            }
        }
        // ---- GEMM2: acc2[ntj][r] = sum_k prow[ntj*16+q*4+r][k] * Z[i0+col][k] ----
#pragma unroll
        for (int kc = 0; kc < 4; kc++)
#pragma unroll
            for (int ntj = 0; ntj < 4; ntj++) {
                acc2[ntj] = __builtin_amdgcn_mfma_f32_16x16x16bf16_1k(prH[kc][ntj], zH[kc], acc2[ntj], 0, 0, 0);
                acc2[ntj] = __builtin_amdgcn_mfma_f32_16x16x16bf16_1k(prL[kc][ntj], zH[kc], acc2[ntj], 0, 0, 0);
                acc2[ntj] = __builtin_amdgcn_mfma_f32_16x16x16bf16_1k(prH[kc][ntj], zL[kc], acc2[ntj], 0, 0, 0);
            }
#else
        // fallback: Z via LDS (R6 path)
#pragma unroll
        for (int nt = 0; nt < 4; nt++) {
            u16 hh[4], ll[4];
#pragma unroll
            for (int r = 0; r < 4; r++) {
                float v = acc[nt][r];
                u16 h = f2bf(v);
                hh[r] = h;
                ll[r] = f2bf(v - bf2f(h));
            }
            int zi = (i0 + col) * LDX + nt * 16 + q * 4;
            *(unsigned long long*)&Zh[zi] =
                (unsigned long long)hh[0] | ((unsigned long long)hh[1] << 16) |
                ((unsigned long long)hh[2] << 32) | ((unsigned long long)hh[3] << 48);
            *(unsigned long long*)&Zl[zi] =
                (unsigned long long)ll[0] | ((unsigned long long)ll[1] << 16) |
                ((unsigned long long)ll[2] << 32) | ((unsigned long long)ll[3] << 48);
        }
#pragma unroll
        for (int ks = 0; ks < 2; ks++) {
            bf16x8 zh8 = *(const bf16x8*)&Zh[(i0 + col) * LDX + q * 8 + ks * 32];
            bf16x8 zl8 = *(const bf16x8*)&Zl[(i0 + col) * LDX + q * 8 + ks * 32];
#pragma unroll
            for (int ntj = 0; ntj < 4; ntj++) {
                acc2[ntj] = __builtin_amdgcn_mfma_f32_16x16x32_bf16(prA_h[ks][ntj], zh8, acc2[ntj], 0, 0, 0);
                acc2[ntj] = __builtin_amdgcn_mfma_f32_16x16x32_bf16(prA_l[ks][ntj], zh8, acc2[ntj], 0, 0, 0);
                acc2[ntj] = __builtin_amdgcn_mfma_f32_16x16x32_bf16(prA_h[ks][ntj], zl8, acc2[ntj], 0, 0, 0);
            }
        }
#endif
        // ---- packed out store ----
        float* oc = out + ((size_t)b * C_ + cbase + ci) * PIX_;
#pragma unroll
        for (int ntj = 0; ntj < 4; ntj++) {
            float4 vv = {acc2[ntj][0], acc2[ntj][1], acc2[ntj][2], acc2[ntj][3]};
            *(float4*)&oc[(i0 + col) * 64 + ntj * 16 + q * 4] = vv;
        }

        // ---- convert + write next channel into the other buffer ----
        if (ci < 3) {
            const int nxt = cur ^ 1;
#pragma unroll
            for (int k = 0; k < 4; k++) {
                int f = t + k * 256;
                int rw = f >> 4, c4 = f & 15;
                float4 v = pv[k];
                u16 h0 = f2bf(v.x), h1 = f2bf(v.y), h2 = f2bf(v.z), h3 = f2bf(v.w);
                ushort4 hv = {h0, h1, h2, h3};
                ushort4 lv = {f2bf(v.x - bf2f(h0)), f2bf(v.y - bf2f(h1)),
                              f2bf(v.z - bf2f(h2)), f2bf(v.w - bf2f(h3))};
                *(ushort4*)&Xh[nxt][rw * LDX + c4 * 4] = hv;
                *(ushort4*)&Xl[nxt][rw * LDX + c4 * 4] = lv;
            }
        }
    }
}

extern "C" void kernel_launch(void* const* d_in, const int* in_sizes, int n_in,
                              void* d_out, int out_size, void* d_ws, size_t ws_size,
                              hipStream_t stream) {
    const float* x = (const float*)d_in[0];
    const float* w1 = (const float*)d_in[1];
    const float* b1 = (const float*)d_in[2];
    const float* w2 = (const float*)d_in[3];
    const float* b2 = (const float*)d_in[4];
    const float* w_row = (const float*)d_in[5];
    const float* b_row = (const float*)d_in[6];
    const float* w_col = (const float*)d_in[7];
    const float* b_col = (const float*)d_in[8];
    float* out = (float*)d_out;

    char* ws = (char*)d_ws;
    u16* w1h = (u16*)(ws);                   //  65536 B
    u16* w1l = (u16*)(ws + 65536);           //  65536 B
    u16* w2h = (u16*)(ws + 131072);          //  131072 B
    u16* w2l = (u16*)(ws + 262144);          //  131072 B
    float* row_s = (float*)(ws + 393216);    //  8192 B
    float* col_s = (float*)(ws + 401408);    //  8192 B
    u16* prow_h = (u16*)(ws + 409600);       //  262144 B
    u16* prow_l = (u16*)(ws + 671744);       //  262144 B
    u16* pcol_h = (u16*)(ws + 933888);       //  262144 B
    u16* pcol_l = (u16*)(ws + 1196032);      //  262144 B

    hipLaunchKernelGGL(k_prep, dim3(384), dim3(256), 0, stream, w1, w2, w1h, w1l, w2h, w2l,
                       col_s, b_col);
    hipLaunchKernelGGL(k12_fused, dim3(64, 32), dim3(512), 0, stream,
                       x, w1h, w1l, b1, w2h, w2l, b2, w_row, b_row, w_col, row_s, col_s);
    hipLaunchKernelGGL(k4_diffsort, dim3(64), dim3(256), 0, stream,
                       row_s, col_s, prow_h, prow_l, pcol_h, pcol_l);
    hipLaunchKernelGGL(k5_permute, dim3(32, 32), dim3(256), 0, stream,
                       x, pcol_h, pcol_l, prow_h, prow_l, out);
}